// Round 17
// baseline (181.264 us; speedup 1.0000x reference)
//
#include <hip/hip_runtime.h>

using u16 = unsigned short;
using u32 = unsigned int;
using short8 = __attribute__((ext_vector_type(8))) short;
using short4v = __attribute__((ext_vector_type(4))) short;
using bf16x8 = __attribute__((ext_vector_type(8))) __bf16;
using f32x4 = __attribute__((ext_vector_type(4))) float;

#define ALPHA_INV (1.0f / (128.0f * 100.0f))

__device__ __forceinline__ u32 swz(u32 off, u32 row) { return off ^ ((row & 7u) << 4); }

__device__ __forceinline__ u16 f2bf(float x) {
  u32 u = __float_as_uint(x);
  u32 r = u + 0x7fffu + ((u >> 16) & 1u);
  return (u16)(r >> 16);
}

__device__ __forceinline__ float bf2f(u16 x) {
  u32 u = ((u32)x) << 16;
  return __uint_as_float(u);
}

__device__ __forceinline__ f32x4 mfma(bf16x8 a, bf16x8 b, f32x4 c) {
  return __builtin_amdgcn_mfma_f32_16x16x32_bf16(a, b, c, 0, 0, 0);
}

// async 16B global->LDS; LDS dest is wave-uniform base + lane*16
__device__ __forceinline__ void gl16(const void* g, void* l) {
  __builtin_amdgcn_global_load_lds(
      (const __attribute__((address_space(1))) unsigned int*)g,
      (__attribute__((address_space(3))) unsigned int*)l, 16, 0, 0);
}

// ---------------------------------------------------------------------------
// prep: weights transpose+bf16+pre-swizzle + batch fp32 -> ST (own region).
// ---------------------------------------------------------------------------
__global__ __launch_bounds__(256) void prep(
    const float* __restrict__ batch,
    const float* __restrict__ w0, const float* __restrict__ w1,
    const float* __restrict__ w2, const float* __restrict__ wo,
    u16* __restrict__ o0, u16* __restrict__ o1,
    u16* __restrict__ o2, u16* __restrict__ o3,
    u16* __restrict__ ST) {
  __shared__ u16 L[64 * 129];
  int blk = blockIdx.x;
  if (blk < 1536) {
    const float* w; u16* o; int cin;
    if (blk < 256)       { w = w0; o = o0; cin = 128; }
    else if (blk < 768)  { w = w1; o = o1; cin = 256; blk -= 256; }
    else if (blk < 1280) { w = w2; o = o2; cin = 256; blk -= 768; }
    else                 { w = wo; o = o3; cin = 256; blk -= 1280; }
    int idx = blk * 256 + threadIdx.x;
    int row = idx >> 8, n = idx & 255;
    int tap = row / cin, c = row - tap * cin;
    int kc = c >> 6, ci = c & 63;
    u32 sb = (u32)(ci * 2) ^ ((u32)(n & 7) << 4);
    o[((size_t)tap * 256 + n) * cin + kc * 64 + (sb >> 1)] = f2bf(w[idx]);
    return;
  }
  blk -= 1536;
  const int tid = threadIdx.x;
  const int t0 = (blk & 31) * 64;
  const int b = blk >> 5;
  const float* src = batch + ((size_t)b * 2048 + t0) * 128;
#pragma unroll
  for (int it = 0; it < 4; ++it) {
    int s = tid + it * 256;
    int t = s >> 4, c8 = s & 15;
    float4 v0 = *(const float4*)(src + t * 128 + c8 * 8);
    float4 v1 = *(const float4*)(src + t * 128 + c8 * 8 + 4);
    u16* p = &L[t * 129 + c8 * 8];
    p[0] = f2bf(v0.x); p[1] = f2bf(v0.y); p[2] = f2bf(v0.z); p[3] = f2bf(v0.w);
    p[4] = f2bf(v1.x); p[5] = f2bf(v1.y); p[6] = f2bf(v1.z); p[7] = f2bf(v1.w);
  }
  __syncthreads();
  u16* dst = ST + (size_t)b * 128 * 2048 + t0;
#pragma unroll
  for (int it = 0; it < 4; ++it) {
    int s = tid + it * 256;
    int oct = s & 7, d = s >> 3;
    short8 v;
#pragma unroll
    for (int j = 0; j < 8; ++j) v[j] = (short)L[(oct * 8 + j) * 129 + d];
    *(short8*)(dst + (size_t)d * 2048 + oct * 8) = v;
  }
}

// ---------------------------------------------------------------------------
// conv_first: CIN=128, 2 taps, dil=1, ReLU. Input = fp32 batch. (R13-proven)
// ---------------------------------------------------------------------------
__global__ __launch_bounds__(512) void conv_first(
    const float* __restrict__ in, const u16* __restrict__ wt,
    const float* __restrict__ bias, u16* __restrict__ out) {
  constexpr int CIN = 128, BN = 256;
  __shared__ alignas(16) u16 Al[128 * 64];
  __shared__ alignas(16) u16 Bl[256 * 64];

  const int tid = threadIdx.x;
  const int wid = tid >> 6, lane = tid & 63;
  const int wr = wid >> 2, wc = wid & 3;
  const int lg = lane >> 4, lq = lane & 15;
  const int row0 = blockIdx.x * 128;
  const int tloc0 = row0 & 2047;

  f32x4 acc[4][4];
#pragma unroll
  for (int i = 0; i < 4; ++i)
#pragma unroll
    for (int j = 0; j < 4; ++j) acc[i][j] = (f32x4)0.0f;

#pragma unroll
  for (int tap = 0; tap < 2; ++tap) {
    const int shift = 1 - tap;
#pragma unroll
    for (int kc = 0; kc < 2; ++kc) {
#pragma unroll
      for (int it = 0; it < 2; ++it) {
        int gi = tid + it * 512;
        int r = gi >> 3, cg = gi & 7;
        short8 v = (short8)0;
        if (!(tloc0 == 0 && r < shift)) {
          const float* src = in + (size_t)(row0 + r - shift) * CIN + kc * 64 + cg * 8;
          float4 a = *(const float4*)src;
          float4 b2 = *(const float4*)(src + 4);
          v[0] = (short)f2bf(a.x);  v[1] = (short)f2bf(a.y);
          v[2] = (short)f2bf(a.z);  v[3] = (short)f2bf(a.w);
          v[4] = (short)f2bf(b2.x); v[5] = (short)f2bf(b2.y);
          v[6] = (short)f2bf(b2.z); v[7] = (short)f2bf(b2.w);
        }
        *(short8*)((char*)Al + swz(r * 128 + cg * 16, (u32)(r - shift + 8))) = v;
      }
      {
        const u16* wtb = wt + ((size_t)(tap * 256)) * CIN + kc * 64;
#pragma unroll
        for (int it = 0; it < 4; ++it) {
          int gi = tid + it * 512;
          int n = gi >> 3, cg = gi & 7;
          gl16(wtb + (size_t)n * CIN + cg * 8, (char*)Bl + it * 8192 + wid * 1024);
        }
      }
      __syncthreads();
#pragma unroll
      for (int ks = 0; ks < 2; ++ks) {
        bf16x8 af[4], bfr[4];
#pragma unroll
        for (int mi = 0; mi < 4; ++mi) {
          int r = wr * 64 + mi * 16 + lq;
          af[mi] = *(const bf16x8*)((const char*)Al +
                                    swz(r * 128 + ks * 64 + lg * 16, (u32)(r - shift + 8)));
        }
#pragma unroll
        for (int ni = 0; ni < 4; ++ni) {
          int n = wc * 64 + ni * 16 + lq;
          bfr[ni] = *(const bf16x8*)((const char*)Bl + swz(n * 128 + ks * 64 + lg * 16, n));
        }
#pragma unroll
        for (int mi = 0; mi < 4; ++mi)
#pragma unroll
          for (int ni = 0; ni < 4; ++ni)
            acc[mi][ni] = mfma(af[mi], bfr[ni], acc[mi][ni]);
      }
      __syncthreads();
    }
  }

  float bcol[4];
#pragma unroll
  for (int ni = 0; ni < 4; ++ni) bcol[ni] = bias[wc * 64 + ni * 16 + lq];
#pragma unroll
  for (int mi = 0; mi < 4; ++mi)
#pragma unroll
    for (int ni = 0; ni < 4; ++ni)
#pragma unroll
      for (int rr = 0; rr < 4; ++rr) {
        float v = fmaxf(acc[mi][ni][rr] + bcol[ni], 0.0f);
        int row = row0 + wr * 64 + mi * 16 + lg * 4 + rr;
        int col = wc * 64 + ni * 16 + lq;
        int ci = col & 63;
        u32 sb = (u32)(ci * 2) ^ ((u32)(row & 7) << 4);
        out[(size_t)row * BN + wc * 64 + (sb >> 1)] = f2bf(v);
      }
}

// ---------------------------------------------------------------------------
// conv_mid<DIL>, 2-PHASE (race-free): per tile: issue next-tile gl16s ->
// compute current -> vmcnt(0)+barrier. Reads of a buffer always complete
// (MFMA-consumed) before the barrier that precedes its re-staging.
// ---------------------------------------------------------------------------
template <int DIL>
__global__ __launch_bounds__(512) void conv_mid(
    const u16* __restrict__ in, const u16* __restrict__ wt,
    const float* __restrict__ bias, u16* __restrict__ out) {
  constexpr int CIN = 256, BN = 256;
  __shared__ alignas(16) u16 Al[2][136 * 64];
  __shared__ alignas(16) u16 Bl[2][256 * 64];

  const int tid = threadIdx.x;
  const int wid = tid >> 6, lane = tid & 63;
  const int wr = wid >> 2, wc = wid & 3;
  const int lg = lane >> 4, lq = lane & 15;
  const int row0 = blockIdx.x * 128;
  const int tloc0 = row0 & 2047;

  f32x4 acc[4][4];
#pragma unroll
  for (int i = 0; i < 4; ++i)
#pragma unroll
    for (int j = 0; j < 4; ++j) acc[i][j] = (f32x4)0.0f;

#define STAGE_MID(BUF, KC, TAP)                                                          \
  {                                                                                      \
    _Pragma("unroll") for (int p = 0; p < 2; ++p) {                                      \
      int gi = tid + p * 512;                                                            \
      gl16(in + (size_t)(row0 - DIL + (gi >> 3)) * CIN + (KC)*64 + (gi & 7) * 8,         \
           (char*)Al[BUF] + p * 8192 + wid * 1024);                                      \
    }                                                                                    \
    if (wid == 0)                                                                        \
      gl16(in + (size_t)(row0 - DIL + 128 + (lane >> 3)) * CIN + (KC)*64 + (lane & 7) * 8,\
           (char*)Al[BUF] + 16384);                                                      \
    const u16* wtb = wt + (size_t)(TAP)*256 * CIN + (KC)*64;                             \
    _Pragma("unroll") for (int p = 0; p < 4; ++p) {                                      \
      int gi = tid + p * 512;                                                            \
      gl16(wtb + (size_t)(gi >> 3) * CIN + (gi & 7) * 8,                                 \
           (char*)Bl[BUF] + p * 8192 + wid * 1024);                                      \
    }                                                                                    \
  }

  STAGE_MID(0, 0, 0);
  asm volatile("s_waitcnt vmcnt(0)" ::: "memory");
  __builtin_amdgcn_s_barrier();

#pragma unroll
  for (int it8 = 0; it8 < 8; ++it8) {
    const int buf = it8 & 1;
    const int tap = it8 & 1;        // iteration = (kc, tap): tap fast
    // issue next tile early (hidden under this tile's compute)
    if (it8 < 7) {
      STAGE_MID((it8 + 1) & 1, (it8 + 1) >> 1, (it8 + 1) & 1);
    }
    if (tap == 0 && tloc0 == 0) {  // zero garbage rows < DIL (block-uniform)
      if (tid < DIL * 8) *(short8*)((char*)Al[buf] + tid * 16) = (short8)0;
      asm volatile("s_waitcnt lgkmcnt(0)" ::: "memory");
      __builtin_amdgcn_s_barrier();
    }
#pragma unroll
    for (int ks = 0; ks < 2; ++ks) {
      bf16x8 af[4], bfr[4];
#pragma unroll
      for (int mi = 0; mi < 4; ++mi) {
        int r = wr * 64 + mi * 16 + lq;
        if (tap == 0)
          af[mi] = *(const bf16x8*)((const char*)Al[buf] +
                                    swz(r * 128 + ks * 64 + lg * 16, (u32)(r - DIL + 8)));
        else
          af[mi] = *(const bf16x8*)((const char*)Al[buf] +
                                    swz((r + DIL) * 128 + ks * 64 + lg * 16, (u32)(r + 8)));
      }
#pragma unroll
      for (int ni = 0; ni < 4; ++ni) {
        int n = wc * 64 + ni * 16 + lq;
        bfr[ni] = *(const bf16x8*)((const char*)Bl[buf] + swz(n * 128 + ks * 64 + lg * 16, n));
      }
#pragma unroll
      for (int mi = 0; mi < 4; ++mi)
#pragma unroll
        for (int ni = 0; ni < 4; ++ni)
          acc[mi][ni] = mfma(af[mi], bfr[ni], acc[mi][ni]);
    }
    if (it8 < 7) {
      asm volatile("s_waitcnt vmcnt(0)" ::: "memory");  // drain next-tile loads (hidden above)
      __builtin_amdgcn_s_barrier();
    }
  }
#undef STAGE_MID

  float bcol[4];
#pragma unroll
  for (int ni = 0; ni < 4; ++ni) bcol[ni] = bias[wc * 64 + ni * 16 + lq];
#pragma unroll
  for (int mi = 0; mi < 4; ++mi)
#pragma unroll
    for (int ni = 0; ni < 4; ++ni)
#pragma unroll
      for (int rr = 0; rr < 4; ++rr) {
        float v = fmaxf(acc[mi][ni][rr] + bcol[ni], 0.0f);
        int row = row0 + wr * 64 + mi * 16 + lg * 4 + rr;
        int col = wc * 64 + ni * 16 + lq;
        int ci = col & 63;
        u32 sb = (u32)(ci * 2) ^ ((u32)(row & 7) << 4);
        out[(size_t)row * BN + wc * 64 + (sb >> 1)] = f2bf(v);
      }
}

// ---------------------------------------------------------------------------
// conv_last, 2-PHASE (race-free, same discipline). Fused softmax epilogue.
// ---------------------------------------------------------------------------
__global__ __launch_bounds__(512) void conv_last(
    const u16* __restrict__ in, const u16* __restrict__ wt,
    const float* __restrict__ bias, u16* __restrict__ out) {
  constexpr int CIN = 256, BN = 256;
  __shared__ alignas(16) u16 Al[2][128 * 64];
  __shared__ alignas(16) u16 Bl[2][256 * 64];
  __shared__ float redA[4][128];
  __shared__ float redB[4][128];

  const int tid = threadIdx.x;
  const int wid = tid >> 6, lane = tid & 63;
  const int wr = wid >> 2, wc = wid & 3;
  const int lg = lane >> 4, lq = lane & 15;
  const int row0 = blockIdx.x * 128;

  f32x4 acc[4][4];
#pragma unroll
  for (int i = 0; i < 4; ++i)
#pragma unroll
    for (int j = 0; j < 4; ++j) acc[i][j] = (f32x4)0.0f;

#define STAGE_LAST(BUF, KC)                                                              \
  {                                                                                      \
    _Pragma("unroll") for (int p = 0; p < 2; ++p) {                                      \
      int gi = tid + p * 512;                                                            \
      gl16(in + (size_t)(row0 + (gi >> 3)) * CIN + (KC)*64 + (gi & 7) * 8,               \
           (char*)Al[BUF] + p * 8192 + wid * 1024);                                      \
    }                                                                                    \
    const u16* wtb = wt + (KC)*64;                                                       \
    _Pragma("unroll") for (int p = 0; p < 4; ++p) {                                      \
      int gi = tid + p * 512;                                                            \
      gl16(wtb + (size_t)(gi >> 3) * CIN + (gi & 7) * 8,                                 \
           (char*)Bl[BUF] + p * 8192 + wid * 1024);                                      \
    }                                                                                    \
  }

  STAGE_LAST(0, 0);
  asm volatile("s_waitcnt vmcnt(0)" ::: "memory");
  __builtin_amdgcn_s_barrier();

#pragma unroll
  for (int it4 = 0; it4 < 4; ++it4) {
    const int buf = it4 & 1;
    if (it4 < 3) {
      STAGE_LAST((it4 + 1) & 1, it4 + 1);
    }
#pragma unroll
    for (int ks = 0; ks < 2; ++ks) {
      bf16x8 af[4], bfr[4];
#pragma unroll
      for (int mi = 0; mi < 4; ++mi) {
        int r = wr * 64 + mi * 16 + lq;
        af[mi] = *(const bf16x8*)((const char*)Al[buf] +
                                  swz(r * 128 + ks * 64 + lg * 16, (u32)(r + 8)));
      }
#pragma unroll
      for (int ni = 0; ni < 4; ++ni) {
        int n = wc * 64 + ni * 16 + lq;
        bfr[ni] = *(const bf16x8*)((const char*)Bl[buf] + swz(n * 128 + ks * 64 + lg * 16, n));
      }
#pragma unroll
      for (int mi = 0; mi < 4; ++mi)
#pragma unroll
        for (int ni = 0; ni < 4; ++ni)
          acc[mi][ni] = mfma(af[mi], bfr[ni], acc[mi][ni]);
    }
    if (it4 < 3) {
      asm volatile("s_waitcnt vmcnt(0)" ::: "memory");
      __builtin_amdgcn_s_barrier();
    }
  }
#undef STAGE_LAST
  __syncthreads();

  float bcol[4];
#pragma unroll
  for (int ni = 0; ni < 4; ++ni) bcol[ni] = bias[wc * 64 + ni * 16 + lq];
#pragma unroll
  for (int mi = 0; mi < 4; ++mi)
#pragma unroll
    for (int ni = 0; ni < 4; ++ni)
#pragma unroll
      for (int rr = 0; rr < 4; ++rr) acc[mi][ni][rr] += bcol[ni];

  float tmx[4][4];
#pragma unroll
  for (int mi = 0; mi < 4; ++mi)
#pragma unroll
    for (int rr = 0; rr < 4; ++rr) {
      float v = fmaxf(fmaxf(acc[mi][0][rr], acc[mi][1][rr]),
                      fmaxf(acc[mi][2][rr], acc[mi][3][rr]));
#pragma unroll
      for (int off = 1; off < 16; off <<= 1) v = fmaxf(v, __shfl_xor(v, off));
      if (lq == 0) redA[wc][wr * 64 + mi * 16 + lg * 4 + rr] = v;
    }
  __syncthreads();
#pragma unroll
  for (int mi = 0; mi < 4; ++mi)
#pragma unroll
    for (int rr = 0; rr < 4; ++rr) {
      int rb = wr * 64 + mi * 16 + lg * 4 + rr;
      tmx[mi][rr] = fmaxf(fmaxf(redA[0][rb], redA[1][rb]),
                          fmaxf(redA[2][rb], redA[3][rb]));
    }
#pragma unroll
  for (int mi = 0; mi < 4; ++mi)
#pragma unroll
    for (int rr = 0; rr < 4; ++rr) {
      float s = 0.0f;
#pragma unroll
      for (int ni = 0; ni < 4; ++ni) {
        float p = __expf(acc[mi][ni][rr] - tmx[mi][rr]);
        acc[mi][ni][rr] = p;
        s += p;
      }
#pragma unroll
      for (int off = 1; off < 16; off <<= 1) s += __shfl_xor(s, off);
      if (lq == 0) redB[wc][wr * 64 + mi * 16 + lg * 4 + rr] = s;
    }
  __syncthreads();
#pragma unroll
  for (int mi = 0; mi < 4; ++mi)
#pragma unroll
    for (int rr = 0; rr < 4; ++rr) {
      int rb = wr * 64 + mi * 16 + lg * 4 + rr;
      float inv = 1.0f / (redB[0][rb] + redB[1][rb] + redB[2][rb] + redB[3][rb]);
      int row = row0 + rb;
#pragma unroll
      for (int ni = 0; ni < 4; ++ni) {
        int col = wc * 64 + ni * 16 + lq;
        out[(size_t)row * BN + col] = f2bf(acc[mi][ni][rr] * inv);
      }
    }
}

// ---------------------------------------------------------------------------
// gchunk (unchanged)
// ---------------------------------------------------------------------------
__global__ __launch_bounds__(512) void gchunk(
    const u16* __restrict__ H, const u16* __restrict__ ST,
    u16* __restrict__ G0, u16* __restrict__ G1) {
  constexpr int M = 256, T = 2048;
  __shared__ alignas(16) u16 Hl[128 * 128];
  __shared__ alignas(16) u16 Sl[128 * 128];
  const int tid = threadIdx.x;
  const int wid = tid >> 6, lane = tid & 63;
  const int dg = wid >> 2, mg = wid & 3;
  const int lg = lane >> 4, lq = lane & 15;
  const int b = blockIdx.x, mh = blockIdx.y, j = blockIdx.z;
  u16* G = (mh == 0 ? G0 : G1);

#pragma unroll
  for (int it = 0; it < 4; ++it) {
    int s = tid + it * 512;
    int t = s >> 4, c8 = s & 15;
    short8 v = *(const short8*)(H + ((size_t)b * T + j * 128 + t) * M + mh * 128 + c8 * 8);
#pragma unroll
    for (int jj = 0; jj < 8; ++jj) {
      int ml = c8 * 8 + jj;
      *(u16*)((char*)Hl + swz(ml * 256 + t * 2, ml)) = (u16)v[jj];
    }
  }
#pragma unroll
  for (int it = 0; it < 4; ++it) {
    int s = tid + it * 512;
    int d = s >> 4, c8 = s & 15;
    *(short8*)((char*)Sl + swz(d * 256 + c8 * 16, d)) =
        *(const short8*)(ST + ((size_t)b * 128 + d) * T + j * 128 + c8 * 8);
  }
  __syncthreads();

  f32x4 acc[4][2];
#pragma unroll
  for (int di = 0; di < 4; ++di)
#pragma unroll
    for (int mi = 0; mi < 2; ++mi) acc[di][mi] = (f32x4)0.0f;

#pragma unroll
  for (int ks = 0; ks < 4; ++ks) {
    bf16x8 sfrag[4];
#pragma unroll
    for (int di = 0; di < 4; ++di) {
      int d = dg * 64 + di * 16 + lq;
      sfrag[di] = *(const bf16x8*)((const char*)Sl + swz(d * 256 + ks * 64 + lg * 16, d));
    }
#pragma unroll
    for (int mi = 0; mi < 2; ++mi) {
      int ml = mg * 32 + mi * 16 + lq;
      bf16x8 hfrag =
          *(const bf16x8*)((const char*)Hl + swz(ml * 256 + ks * 64 + lg * 16, ml));
#pragma unroll
      for (int di = 0; di < 4; ++di) acc[di][mi] = mfma(sfrag[di], hfrag, acc[di][mi]);
    }
  }

  u16* Gj = G + (((size_t)b * 16 + j) << 14);
#pragma unroll
  for (int di = 0; di < 4; ++di)
#pragma unroll
    for (int mi = 0; mi < 2; ++mi)
#pragma unroll
      for (int rr = 0; rr < 4; ++rr) {
        int d = dg * 64 + di * 16 + lg * 4 + rr;
        int ml = mg * 32 + mi * 16 + lq;
        Gj[d * 128 + ml] = f2bf(acc[di][mi][rr]);
      }
}

// ---------------------------------------------------------------------------
// prefix_wfin (unchanged)
// ---------------------------------------------------------------------------
__global__ __launch_bounds__(256) void prefix_wfin(
    u16* __restrict__ G0, u16* __restrict__ G1, float* __restrict__ wfin) {
  __shared__ float Wl[16][132];
  const int b = blockIdx.x, mh = blockIdx.y, ds = blockIdx.z;
  u16* G = mh ? G1 : G0;
  const int tid = threadIdx.x;
  const int mo = tid & 15, dg = tid >> 4;
  const int d = ds * 16 + dg;
  size_t base = (((size_t)b * 16) << 14) + d * 128 + mo * 8;
  float acc[8];
#pragma unroll
  for (int k = 0; k < 8; ++k) acc[k] = ALPHA_INV;
  for (int j = 0; j < 16; ++j) {
    u16* p = G + base + ((size_t)j << 14);
    short8 g = *(short8*)p;
    short8 c;
#pragma unroll
    for (int k = 0; k < 8; ++k) c[k] = (short)f2bf(acc[k]);
    *(short8*)p = c;
#pragma unroll
    for (int k = 0; k < 8; ++k) acc[k] += bf2f((u16)g[k]);
  }
#pragma unroll
  for (int k = 0; k < 8; ++k) Wl[dg][mo * 8 + k] = acc[k];
  __syncthreads();
  const int ml = tid >> 1, dq = tid & 1;
  const int dl0 = dq * 8;
  float* dst = wfin + ((size_t)b * 256 + mh * 128 + ml) * 128 + ds * 16 + dl0;
  float4 v0 = make_float4(Wl[dl0][ml], Wl[dl0 + 1][ml], Wl[dl0 + 2][ml], Wl[dl0 + 3][ml]);
  float4 v1 = make_float4(Wl[dl0 + 4][ml], Wl[dl0 + 5][ml], Wl[dl0 + 6][ml], Wl[dl0 + 7][ml]);
  *(float4*)dst = v0;
  *(float4*)(dst + 4) = v1;
}

// ---------------------------------------------------------------------------
// attn_chunk (R13-proven, 3 barriers, Hi from registers)
// ---------------------------------------------------------------------------
__global__ __launch_bounds__(512) void attn_chunk(
    const u16* __restrict__ H, const u16* __restrict__ ST,
    const u16* __restrict__ C0, const u16* __restrict__ C1,
    float* __restrict__ out) {
  constexpr int M = 256, D = 128, T = 2048;
  __shared__ alignas(16) u16 Hi[128 * 256];
  __shared__ alignas(16) u16 Sl[128 * 128];
  __shared__ alignas(16) u16 Ct[128 * 128];

  const int tid = threadIdx.x;
  const int wid = tid >> 6, lane = tid & 63;
  const int lg = lane >> 4, lq = lane & 15;
  const int b = blockIdx.x, i = blockIdx.y;
  const size_t hrow0 = (size_t)b * T + i * 128;
  const size_t coff = ((size_t)b * 16 + i) * (128 * 128);

  bf16x8 aq[8];
  {
    const u16* qrow = H + (hrow0 + wid * 16 + lq) * M;
#pragma unroll
    for (int ks = 0; ks < 8; ++ks) aq[ks] = *(const bf16x8*)(qrow + ks * 32 + lg * 8);
  }

  short8 ct1r[4];
#pragma unroll
  for (int it = 0; it < 4; ++it) {
    int s = tid + it * 512;
    int d = s >> 4, c8 = s & 15;
    ct1r[it] = *(const short8*)(C1 + coff + d * 128 + c8 * 8);
  }

  {
    int r = wid * 16 + lq;
#pragma unroll
    for (int ks = 0; ks < 8; ++ks)
      *(short8*)((char*)Hi + swz(r * 512 + ks * 64 + lg * 16, r)) =
          __builtin_bit_cast(short8, aq[ks]);
  }
#pragma unroll
  for (int it = 0; it < 4; ++it) {
    int s = tid + it * 512;
    int d = s >> 4, c8 = s & 15;
    *(short8*)((char*)Sl + swz(d * 256 + c8 * 16, d)) =
        *(const short8*)(ST + ((size_t)b * D + d) * T + i * 128 + c8 * 8);
  }
#pragma unroll
  for (int it = 0; it < 4; ++it) {
    int s = tid + it * 512;
    int d = s >> 4, c8 = s & 15;
    *(short8*)((char*)Ct + swz(d * 256 + c8 * 16, d)) = *(const short8*)(C0 + coff + d * 128 + c8 * 8);
  }
  __syncthreads();

  f32x4 accO[8];
#pragma unroll
  for (int df = 0; df < 8; ++df) accO[df] = (f32x4)0.0f;
#pragma unroll
  for (int ks = 0; ks < 4; ++ks)
#pragma unroll
    for (int df = 0; df < 8; ++df) {
      int d = df * 16 + lq;
      bf16x8 bf = *(const bf16x8*)((const char*)Ct + swz(d * 256 + ks * 64 + lg * 16, d));
      accO[df] = mfma(aq[ks], bf, accO[df]);
    }
  f32x4 accP[8];
#pragma unroll
  for (int cf = 0; cf < 8; ++cf) accP[cf] = (f32x4)0.0f;
#pragma unroll
  for (int ks = 0; ks < 8; ++ks)
#pragma unroll
    for (int cf = 0; cf < 8; ++cf) {
      int tt = cf * 16 + lq;
      bf16x8 bf = *(const bf16x8*)((const char*)Hi + swz(tt * 512 + ks * 64 + lg * 16, tt));
      accP[cf] = mfma(aq[ks], bf, accP[cf]);
    }
  __syncthreads();

#pragma unroll
  for (int it = 0; it < 4; ++it) {
    int s = tid + it * 512;
    int d = s >> 4, c8 = s & 15;
    *(short8*)((char*)Ct + swz(d * 256 + c8 * 16, d)) = ct1r[it];
  }
  char* Pw = (char*)Hi + wid * 4096;
#pragma unroll
  for (int cf = 0; cf < 8; ++cf)
#pragma unroll
    for (int rr = 0; rr < 4; ++rr) {
      int ql = lg * 4 + rr;
      int tl = cf * 16 + lq;
      float v = accP[cf][rr];
      if (tl >= wid * 16 + ql) v = 0.0f;
      *(u16*)(Pw + swz(ql * 256 + tl * 2, ql)) = f2bf(v);
    }
  __syncthreads();

#pragma unroll
  for (int ks = 0; ks < 4; ++ks)
#pragma unroll
    for (int df = 0; df < 8; ++df) {
      int d = df * 16 + lq;
      bf16x8 bf = *(const bf16x8*)((const char*)Ct + swz(d * 256 + ks * 64 + lg * 16, d));
      accO[df] = mfma(aq[4 + ks], bf, accO[df]);
    }
#pragma unroll
  for (int ks = 0; ks < 4; ++ks) {
    bf16x8 a = *(const bf16x8*)(Pw + swz(lq * 256 + ks * 64 + lg * 16, lq));
#pragma unroll
    for (int df = 0; df < 8; ++df) {
      int d = df * 16 + lq;
      bf16x8 bf = *(const bf16x8*)((const char*)Sl + swz(d * 256 + ks * 64 + lg * 16, d));
      accO[df] = mfma(a, bf, accO[df]);
    }
  }

#pragma unroll
  for (int rr = 0; rr < 4; ++rr) {
    float ssum = 0.0f;
#pragma unroll
    for (int df = 0; df < 8; ++df) ssum += accO[df][rr];
#pragma unroll
    for (int off = 1; off < 16; off <<= 1) ssum += __shfl_xor(ssum, off);
    float inv = 1.0f / ssum;
    size_t row = hrow0 + wid * 16 + lg * 4 + rr;
#pragma unroll
    for (int df = 0; df < 8; ++df)
      out[row * D + df * 16 + lq] = accO[df][rr] * inv;
  }
}

// ---------------------------------------------------------------------------
extern "C" void kernel_launch(void* const* d_in, const int* in_sizes, int n_in,
                              void* d_out, int out_size, void* d_ws, size_t ws_size,
                              hipStream_t stream) {
  const float* batch = (const float*)d_in[0];
  const float* w0 = (const float*)d_in[1];
  const float* b0 = (const float*)d_in[2];
  const float* w1 = (const float*)d_in[3];
  const float* b1 = (const float*)d_in[4];
  const float* w2 = (const float*)d_in[5];
  const float* b2 = (const float*)d_in[6];
  const float* wo = (const float*)d_in[7];
  const float* bo = (const float*)d_in[8];

  const size_t SZ_S = 16777216;     // 16MB
  const size_t SZ_BUF = 33554432;   // 32MB
  const size_t ST_OFF = 88080384;   // 84MB — ST's own region
  const size_t NEED = ST_OFF + SZ_S;
  if (ws_size < NEED) return;

  char* ws = (char*)d_ws;
  u16* bufA = (u16*)(ws + SZ_S);
  u16* bufB = (u16*)(ws + SZ_S + SZ_BUF);
  u16* Wt0 = (u16*)(ws + SZ_S + 2 * SZ_BUF);
  u16* Wt1 = Wt0 + 2 * 256 * 128;
  u16* Wt2 = Wt1 + 2 * 256 * 256;
  u16* Wt3 = Wt2 + 2 * 256 * 256;
  u16* ST = (u16*)(ws + ST_OFF);
  u16* G0 = (u16*)ws;
  u16* G1 = (u16*)(ws + 2 * SZ_S);
  float* probs = (float*)d_out;
  float* wfin = probs + (size_t)32 * 2048 * 128;

  prep<<<2560, 256, 0, stream>>>(batch, w0, w1, w2, wo, Wt0, Wt1, Wt2, Wt3, ST);

  conv_first<<<512, 512, 0, stream>>>(batch, Wt0, b0, bufA);
  conv_mid<2><<<512, 512, 0, stream>>>(bufA, Wt1, b1, bufB);
  conv_mid<4><<<512, 512, 0, stream>>>(bufB, Wt2, b2, bufA);
  conv_last<<<512, 512, 0, stream>>>(bufA, Wt3, bo, bufB);

  gchunk<<<dim3(32, 2, 16), 512, 0, stream>>>(bufB, ST, G0, G1);
  prefix_wfin<<<dim3(32, 2, 8), 256, 0, stream>>>(G0, G1, wfin);
  attn_chunk<<<dim3(32, 16), 512, 0, stream>>>(bufB, ST, G0, G1, probs);
}

// Round 18
// 174.509 us; speedup vs baseline: 1.0387x; 1.0387x over previous
//
#include <hip/hip_runtime.h>

using u16 = unsigned short;
using u32 = unsigned int;
using short8 = __attribute__((ext_vector_type(8))) short;
using short4v = __attribute__((ext_vector_type(4))) short;
using bf16x8 = __attribute__((ext_vector_type(8))) __bf16;
using f32x4 = __attribute__((ext_vector_type(4))) float;

#define ALPHA_INV (1.0f / (128.0f * 100.0f))

__device__ __forceinline__ u32 swz(u32 off, u32 row) { return off ^ ((row & 7u) << 4); }

__device__ __forceinline__ u16 f2bf(float x) {
  u32 u = __float_as_uint(x);
  u32 r = u + 0x7fffu + ((u >> 16) & 1u);
  return (u16)(r >> 16);
}

__device__ __forceinline__ float bf2f(u16 x) {
  u32 u = ((u32)x) << 16;
  return __uint_as_float(u);
}

__device__ __forceinline__ f32x4 mfma(bf16x8 a, bf16x8 b, f32x4 c) {
  return __builtin_amdgcn_mfma_f32_16x16x32_bf16(a, b, c, 0, 0, 0);
}

// async 16B global->LDS; LDS dest is wave-uniform base + lane*16
__device__ __forceinline__ void gl16(const void* g, void* l) {
  __builtin_amdgcn_global_load_lds(
      (const __attribute__((address_space(1))) unsigned int*)g,
      (__attribute__((address_space(3))) unsigned int*)l, 16, 0, 0);
}

// ---------------------------------------------------------------------------
// prep: weights transpose+bf16+pre-swizzle + batch fp32 -> ST (own region).
// ---------------------------------------------------------------------------
__global__ __launch_bounds__(256) void prep(
    const float* __restrict__ batch,
    const float* __restrict__ w0, const float* __restrict__ w1,
    const float* __restrict__ w2, const float* __restrict__ wo,
    u16* __restrict__ o0, u16* __restrict__ o1,
    u16* __restrict__ o2, u16* __restrict__ o3,
    u16* __restrict__ ST) {
  __shared__ u16 L[64 * 129];
  int blk = blockIdx.x;
  if (blk < 1536) {
    const float* w; u16* o; int cin;
    if (blk < 256)       { w = w0; o = o0; cin = 128; }
    else if (blk < 768)  { w = w1; o = o1; cin = 256; blk -= 256; }
    else if (blk < 1280) { w = w2; o = o2; cin = 256; blk -= 768; }
    else                 { w = wo; o = o3; cin = 256; blk -= 1280; }
    int idx = blk * 256 + threadIdx.x;
    int row = idx >> 8, n = idx & 255;
    int tap = row / cin, c = row - tap * cin;
    int kc = c >> 6, ci = c & 63;
    u32 sb = (u32)(ci * 2) ^ ((u32)(n & 7) << 4);
    o[((size_t)tap * 256 + n) * cin + kc * 64 + (sb >> 1)] = f2bf(w[idx]);
    return;
  }
  blk -= 1536;
  const int tid = threadIdx.x;
  const int t0 = (blk & 31) * 64;
  const int b = blk >> 5;
  const float* src = batch + ((size_t)b * 2048 + t0) * 128;
#pragma unroll
  for (int it = 0; it < 4; ++it) {
    int s = tid + it * 256;
    int t = s >> 4, c8 = s & 15;
    float4 v0 = *(const float4*)(src + t * 128 + c8 * 8);
    float4 v1 = *(const float4*)(src + t * 128 + c8 * 8 + 4);
    u16* p = &L[t * 129 + c8 * 8];
    p[0] = f2bf(v0.x); p[1] = f2bf(v0.y); p[2] = f2bf(v0.z); p[3] = f2bf(v0.w);
    p[4] = f2bf(v1.x); p[5] = f2bf(v1.y); p[6] = f2bf(v1.z); p[7] = f2bf(v1.w);
  }
  __syncthreads();
  u16* dst = ST + (size_t)b * 128 * 2048 + t0;
#pragma unroll
  for (int it = 0; it < 4; ++it) {
    int s = tid + it * 256;
    int oct = s & 7, d = s >> 3;
    short8 v;
#pragma unroll
    for (int j = 0; j < 8; ++j) v[j] = (short)L[(oct * 8 + j) * 129 + d];
    *(short8*)(dst + (size_t)d * 2048 + oct * 8) = v;
  }
}

// ---------------------------------------------------------------------------
// conv_first: CIN=128, 2 taps, dil=1, ReLU. Input = fp32 batch. (R13-proven)
// ---------------------------------------------------------------------------
__global__ __launch_bounds__(512) void conv_first(
    const float* __restrict__ in, const u16* __restrict__ wt,
    const float* __restrict__ bias, u16* __restrict__ out) {
  constexpr int CIN = 128, BN = 256;
  __shared__ alignas(16) u16 Al[128 * 64];
  __shared__ alignas(16) u16 Bl[256 * 64];

  const int tid = threadIdx.x;
  const int wid = tid >> 6, lane = tid & 63;
  const int wr = wid >> 2, wc = wid & 3;
  const int lg = lane >> 4, lq = lane & 15;
  const int row0 = blockIdx.x * 128;
  const int tloc0 = row0 & 2047;

  f32x4 acc[4][4];
#pragma unroll
  for (int i = 0; i < 4; ++i)
#pragma unroll
    for (int j = 0; j < 4; ++j) acc[i][j] = (f32x4)0.0f;

#pragma unroll
  for (int tap = 0; tap < 2; ++tap) {
    const int shift = 1 - tap;
#pragma unroll
    for (int kc = 0; kc < 2; ++kc) {
#pragma unroll
      for (int it = 0; it < 2; ++it) {
        int gi = tid + it * 512;
        int r = gi >> 3, cg = gi & 7;
        short8 v = (short8)0;
        if (!(tloc0 == 0 && r < shift)) {
          const float* src = in + (size_t)(row0 + r - shift) * CIN + kc * 64 + cg * 8;
          float4 a = *(const float4*)src;
          float4 b2 = *(const float4*)(src + 4);
          v[0] = (short)f2bf(a.x);  v[1] = (short)f2bf(a.y);
          v[2] = (short)f2bf(a.z);  v[3] = (short)f2bf(a.w);
          v[4] = (short)f2bf(b2.x); v[5] = (short)f2bf(b2.y);
          v[6] = (short)f2bf(b2.z); v[7] = (short)f2bf(b2.w);
        }
        *(short8*)((char*)Al + swz(r * 128 + cg * 16, (u32)(r - shift + 8))) = v;
      }
      {
        const u16* wtb = wt + ((size_t)(tap * 256)) * CIN + kc * 64;
#pragma unroll
        for (int it = 0; it < 4; ++it) {
          int gi = tid + it * 512;
          int n = gi >> 3, cg = gi & 7;
          gl16(wtb + (size_t)n * CIN + cg * 8, (char*)Bl + it * 8192 + wid * 1024);
        }
      }
      __syncthreads();
#pragma unroll
      for (int ks = 0; ks < 2; ++ks) {
        bf16x8 af[4], bfr[4];
#pragma unroll
        for (int mi = 0; mi < 4; ++mi) {
          int r = wr * 64 + mi * 16 + lq;
          af[mi] = *(const bf16x8*)((const char*)Al +
                                    swz(r * 128 + ks * 64 + lg * 16, (u32)(r - shift + 8)));
        }
#pragma unroll
        for (int ni = 0; ni < 4; ++ni) {
          int n = wc * 64 + ni * 16 + lq;
          bfr[ni] = *(const bf16x8*)((const char*)Bl + swz(n * 128 + ks * 64 + lg * 16, n));
        }
#pragma unroll
        for (int mi = 0; mi < 4; ++mi)
#pragma unroll
          for (int ni = 0; ni < 4; ++ni)
            acc[mi][ni] = mfma(af[mi], bfr[ni], acc[mi][ni]);
      }
      __syncthreads();
    }
  }

  float bcol[4];
#pragma unroll
  for (int ni = 0; ni < 4; ++ni) bcol[ni] = bias[wc * 64 + ni * 16 + lq];
#pragma unroll
  for (int mi = 0; mi < 4; ++mi)
#pragma unroll
    for (int ni = 0; ni < 4; ++ni)
#pragma unroll
      for (int rr = 0; rr < 4; ++rr) {
        float v = fmaxf(acc[mi][ni][rr] + bcol[ni], 0.0f);
        int row = row0 + wr * 64 + mi * 16 + lg * 4 + rr;
        int col = wc * 64 + ni * 16 + lq;
        int ci = col & 63;
        u32 sb = (u32)(ci * 2) ^ ((u32)(row & 7) << 4);
        out[(size_t)row * BN + wc * 64 + (sb >> 1)] = f2bf(v);
      }
}

// ---------------------------------------------------------------------------
// conv_mid<DIL>, 2-PHASE with 3-BUFFER rotation (race-free + deep):
// iter i: [boundary-zero] compute(buf[i%3]); issue STAGE(i+2); counted
// vmcnt(6/7) (awaits STAGE(i+1), issued a full iteration ago); barrier.
// STAGE(i+2) writes buf[(i-1)%3] whose reads completed before bar(i-1). SAFE.
// ---------------------------------------------------------------------------
template <int DIL>
__global__ __launch_bounds__(512) void conv_mid(
    const u16* __restrict__ in, const u16* __restrict__ wt,
    const float* __restrict__ bias, u16* __restrict__ out) {
  constexpr int CIN = 256, BN = 256;
  __shared__ alignas(16) u16 Al[3][136 * 64];
  __shared__ alignas(16) u16 Bl[3][256 * 64];

  const int tid = threadIdx.x;
  const int wid = tid >> 6, lane = tid & 63;
  const int wr = wid >> 2, wc = wid & 3;
  const int lg = lane >> 4, lq = lane & 15;
  const int row0 = blockIdx.x * 128;
  const int tloc0 = row0 & 2047;

  f32x4 acc[4][4];
#pragma unroll
  for (int i = 0; i < 4; ++i)
#pragma unroll
    for (int j = 0; j < 4; ++j) acc[i][j] = (f32x4)0.0f;

#define STAGE_MID(BUF, KC, TAP)                                                          \
  {                                                                                      \
    _Pragma("unroll") for (int p = 0; p < 2; ++p) {                                      \
      int gi = tid + p * 512;                                                            \
      gl16(in + (size_t)(row0 - DIL + (gi >> 3)) * CIN + (KC)*64 + (gi & 7) * 8,         \
           (char*)Al[BUF] + p * 8192 + wid * 1024);                                      \
    }                                                                                    \
    if (wid == 0)                                                                        \
      gl16(in + (size_t)(row0 - DIL + 128 + (lane >> 3)) * CIN + (KC)*64 + (lane & 7) * 8,\
           (char*)Al[BUF] + 16384);                                                      \
    const u16* wtb = wt + (size_t)(TAP)*256 * CIN + (KC)*64;                             \
    _Pragma("unroll") for (int p = 0; p < 4; ++p) {                                      \
      int gi = tid + p * 512;                                                            \
      gl16(wtb + (size_t)(gi >> 3) * CIN + (gi & 7) * 8,                                 \
           (char*)Bl[BUF] + p * 8192 + wid * 1024);                                      \
    }                                                                                    \
  }

  STAGE_MID(0, 0, 0);          // tile 0 = (kc0, tap0)
  STAGE_MID(1, 0, 1);          // tile 1 = (kc0, tap1)
  if (wid == 0)
    asm volatile("s_waitcnt vmcnt(7)" ::: "memory");   // tile 0 landed
  else
    asm volatile("s_waitcnt vmcnt(6)" ::: "memory");
  __builtin_amdgcn_s_barrier();

#pragma unroll
  for (int it8 = 0; it8 < 8; ++it8) {
    const int buf = it8 % 3;
    const int tap = it8 & 1;
    if (tap == 0 && tloc0 == 0) {  // zero garbage rows < DIL (block-uniform)
      if (tid < DIL * 8) *(short8*)((char*)Al[buf] + tid * 16) = (short8)0;
      asm volatile("s_waitcnt lgkmcnt(0)" ::: "memory");
      __builtin_amdgcn_s_barrier();
    }
#pragma unroll
    for (int ks = 0; ks < 2; ++ks) {
      bf16x8 af[4], bfr[4];
#pragma unroll
      for (int mi = 0; mi < 4; ++mi) {
        int r = wr * 64 + mi * 16 + lq;
        if (tap == 0)
          af[mi] = *(const bf16x8*)((const char*)Al[buf] +
                                    swz(r * 128 + ks * 64 + lg * 16, (u32)(r - DIL + 8)));
        else
          af[mi] = *(const bf16x8*)((const char*)Al[buf] +
                                    swz((r + DIL) * 128 + ks * 64 + lg * 16, (u32)(r + 8)));
      }
#pragma unroll
      for (int ni = 0; ni < 4; ++ni) {
        int n = wc * 64 + ni * 16 + lq;
        bfr[ni] = *(const bf16x8*)((const char*)Bl[buf] + swz(n * 128 + ks * 64 + lg * 16, n));
      }
#pragma unroll
      for (int mi = 0; mi < 4; ++mi)
#pragma unroll
        for (int ni = 0; ni < 4; ++ni)
          acc[mi][ni] = mfma(af[mi], bfr[ni], acc[mi][ni]);
    }
    // issue tile it8+2 (safe: its buffer's reads completed before bar(it8-1))
    if (it8 < 6) {
      STAGE_MID((it8 + 2) % 3, (it8 + 2) >> 1, (it8 + 2) & 1);
    }
    if (it8 < 7) {
      if (it8 < 6) {
        if (wid == 0)
          asm volatile("s_waitcnt vmcnt(7)" ::: "memory");  // tile it8+1 landed
        else
          asm volatile("s_waitcnt vmcnt(6)" ::: "memory");
      } else {
        asm volatile("s_waitcnt vmcnt(0)" ::: "memory");    // last tile landed
      }
      __builtin_amdgcn_s_barrier();
    }
  }
#undef STAGE_MID

  float bcol[4];
#pragma unroll
  for (int ni = 0; ni < 4; ++ni) bcol[ni] = bias[wc * 64 + ni * 16 + lq];
#pragma unroll
  for (int mi = 0; mi < 4; ++mi)
#pragma unroll
    for (int ni = 0; ni < 4; ++ni)
#pragma unroll
      for (int rr = 0; rr < 4; ++rr) {
        float v = fmaxf(acc[mi][ni][rr] + bcol[ni], 0.0f);
        int row = row0 + wr * 64 + mi * 16 + lg * 4 + rr;
        int col = wc * 64 + ni * 16 + lq;
        int ci = col & 63;
        u32 sb = (u32)(ci * 2) ^ ((u32)(row & 7) << 4);
        out[(size_t)row * BN + wc * 64 + (sb >> 1)] = f2bf(v);
      }
}

// ---------------------------------------------------------------------------
// conv_last, 2-PHASE with 3-buffer rotation. Fused softmax epilogue.
// ---------------------------------------------------------------------------
__global__ __launch_bounds__(512) void conv_last(
    const u16* __restrict__ in, const u16* __restrict__ wt,
    const float* __restrict__ bias, u16* __restrict__ out) {
  constexpr int CIN = 256, BN = 256;
  __shared__ alignas(16) u16 Al[3][128 * 64];
  __shared__ alignas(16) u16 Bl[3][256 * 64];
  __shared__ float redA[4][128];
  __shared__ float redB[4][128];

  const int tid = threadIdx.x;
  const int wid = tid >> 6, lane = tid & 63;
  const int wr = wid >> 2, wc = wid & 3;
  const int lg = lane >> 4, lq = lane & 15;
  const int row0 = blockIdx.x * 128;

  f32x4 acc[4][4];
#pragma unroll
  for (int i = 0; i < 4; ++i)
#pragma unroll
    for (int j = 0; j < 4; ++j) acc[i][j] = (f32x4)0.0f;

#define STAGE_LAST(BUF, KC)                                                              \
  {                                                                                      \
    _Pragma("unroll") for (int p = 0; p < 2; ++p) {                                      \
      int gi = tid + p * 512;                                                            \
      gl16(in + (size_t)(row0 + (gi >> 3)) * CIN + (KC)*64 + (gi & 7) * 8,               \
           (char*)Al[BUF] + p * 8192 + wid * 1024);                                      \
    }                                                                                    \
    const u16* wtb = wt + (KC)*64;                                                       \
    _Pragma("unroll") for (int p = 0; p < 4; ++p) {                                      \
      int gi = tid + p * 512;                                                            \
      gl16(wtb + (size_t)(gi >> 3) * CIN + (gi & 7) * 8,                                 \
           (char*)Bl[BUF] + p * 8192 + wid * 1024);                                      \
    }                                                                                    \
  }

  STAGE_LAST(0, 0);
  STAGE_LAST(1, 1);
  asm volatile("s_waitcnt vmcnt(6)" ::: "memory");  // tile 0 landed
  __builtin_amdgcn_s_barrier();

#pragma unroll
  for (int it4 = 0; it4 < 4; ++it4) {
    const int buf = it4 % 3;
#pragma unroll
    for (int ks = 0; ks < 2; ++ks) {
      bf16x8 af[4], bfr[4];
#pragma unroll
      for (int mi = 0; mi < 4; ++mi) {
        int r = wr * 64 + mi * 16 + lq;
        af[mi] = *(const bf16x8*)((const char*)Al[buf] +
                                  swz(r * 128 + ks * 64 + lg * 16, (u32)(r + 8)));
      }
#pragma unroll
      for (int ni = 0; ni < 4; ++ni) {
        int n = wc * 64 + ni * 16 + lq;
        bfr[ni] = *(const bf16x8*)((const char*)Bl[buf] + swz(n * 128 + ks * 64 + lg * 16, n));
      }
#pragma unroll
      for (int mi = 0; mi < 4; ++mi)
#pragma unroll
        for (int ni = 0; ni < 4; ++ni)
          acc[mi][ni] = mfma(af[mi], bfr[ni], acc[mi][ni]);
    }
    if (it4 < 2) {
      STAGE_LAST((it4 + 2) % 3, it4 + 2);
    }
    if (it4 < 3) {
      if (it4 < 2)
        asm volatile("s_waitcnt vmcnt(6)" ::: "memory");
      else
        asm volatile("s_waitcnt vmcnt(0)" ::: "memory");
      __builtin_amdgcn_s_barrier();
    }
  }
#undef STAGE_LAST
  __syncthreads();

  float bcol[4];
#pragma unroll
  for (int ni = 0; ni < 4; ++ni) bcol[ni] = bias[wc * 64 + ni * 16 + lq];
#pragma unroll
  for (int mi = 0; mi < 4; ++mi)
#pragma unroll
    for (int ni = 0; ni < 4; ++ni)
#pragma unroll
      for (int rr = 0; rr < 4; ++rr) acc[mi][ni][rr] += bcol[ni];

  float tmx[4][4];
#pragma unroll
  for (int mi = 0; mi < 4; ++mi)
#pragma unroll
    for (int rr = 0; rr < 4; ++rr) {
      float v = fmaxf(fmaxf(acc[mi][0][rr], acc[mi][1][rr]),
                      fmaxf(acc[mi][2][rr], acc[mi][3][rr]));
#pragma unroll
      for (int off = 1; off < 16; off <<= 1) v = fmaxf(v, __shfl_xor(v, off));
      if (lq == 0) redA[wc][wr * 64 + mi * 16 + lg * 4 + rr] = v;
    }
  __syncthreads();
#pragma unroll
  for (int mi = 0; mi < 4; ++mi)
#pragma unroll
    for (int rr = 0; rr < 4; ++rr) {
      int rb = wr * 64 + mi * 16 + lg * 4 + rr;
      tmx[mi][rr] = fmaxf(fmaxf(redA[0][rb], redA[1][rb]),
                          fmaxf(redA[2][rb], redA[3][rb]));
    }
#pragma unroll
  for (int mi = 0; mi < 4; ++mi)
#pragma unroll
    for (int rr = 0; rr < 4; ++rr) {
      float s = 0.0f;
#pragma unroll
      for (int ni = 0; ni < 4; ++ni) {
        float p = __expf(acc[mi][ni][rr] - tmx[mi][rr]);
        acc[mi][ni][rr] = p;
        s += p;
      }
#pragma unroll
      for (int off = 1; off < 16; off <<= 1) s += __shfl_xor(s, off);
      if (lq == 0) redB[wc][wr * 64 + mi * 16 + lg * 4 + rr] = s;
    }
  __syncthreads();
#pragma unroll
  for (int mi = 0; mi < 4; ++mi)
#pragma unroll
    for (int rr = 0; rr < 4; ++rr) {
      int rb = wr * 64 + mi * 16 + lg * 4 + rr;
      float inv = 1.0f / (redB[0][rb] + redB[1][rb] + redB[2][rb] + redB[3][rb]);
      int row = row0 + rb;
#pragma unroll
      for (int ni = 0; ni < 4; ++ni) {
        int col = wc * 64 + ni * 16 + lq;
        out[(size_t)row * BN + col] = f2bf(acc[mi][ni][rr] * inv);
      }
    }
}

// ---------------------------------------------------------------------------
// gchunk (unchanged)
// ---------------------------------------------------------------------------
__global__ __launch_bounds__(512) void gchunk(
    const u16* __restrict__ H, const u16* __restrict__ ST,
    u16* __restrict__ G0, u16* __restrict__ G1) {
  constexpr int M = 256, T = 2048;
  __shared__ alignas(16) u16 Hl[128 * 128];
  __shared__ alignas(16) u16 Sl[128 * 128];
  const int tid = threadIdx.x;
  const int wid = tid >> 6, lane = tid & 63;
  const int dg = wid >> 2, mg = wid & 3;
  const int lg = lane >> 4, lq = lane & 15;
  const int b = blockIdx.x, mh = blockIdx.y, j = blockIdx.z;
  u16* G = (mh == 0 ? G0 : G1);

#pragma unroll
  for (int it = 0; it < 4; ++it) {
    int s = tid + it * 512;
    int t = s >> 4, c8 = s & 15;
    short8 v = *(const short8*)(H + ((size_t)b * T + j * 128 + t) * M + mh * 128 + c8 * 8);
#pragma unroll
    for (int jj = 0; jj < 8; ++jj) {
      int ml = c8 * 8 + jj;
      *(u16*)((char*)Hl + swz(ml * 256 + t * 2, ml)) = (u16)v[jj];
    }
  }
#pragma unroll
  for (int it = 0; it < 4; ++it) {
    int s = tid + it * 512;
    int d = s >> 4, c8 = s & 15;
    *(short8*)((char*)Sl + swz(d * 256 + c8 * 16, d)) =
        *(const short8*)(ST + ((size_t)b * 128 + d) * T + j * 128 + c8 * 8);
  }
  __syncthreads();

  f32x4 acc[4][2];
#pragma unroll
  for (int di = 0; di < 4; ++di)
#pragma unroll
    for (int mi = 0; mi < 2; ++mi) acc[di][mi] = (f32x4)0.0f;

#pragma unroll
  for (int ks = 0; ks < 4; ++ks) {
    bf16x8 sfrag[4];
#pragma unroll
    for (int di = 0; di < 4; ++di) {
      int d = dg * 64 + di * 16 + lq;
      sfrag[di] = *(const bf16x8*)((const char*)Sl + swz(d * 256 + ks * 64 + lg * 16, d));
    }
#pragma unroll
    for (int mi = 0; mi < 2; ++mi) {
      int ml = mg * 32 + mi * 16 + lq;
      bf16x8 hfrag =
          *(const bf16x8*)((const char*)Hl + swz(ml * 256 + ks * 64 + lg * 16, ml));
#pragma unroll
      for (int di = 0; di < 4; ++di) acc[di][mi] = mfma(sfrag[di], hfrag, acc[di][mi]);
    }
  }

  u16* Gj = G + (((size_t)b * 16 + j) << 14);
#pragma unroll
  for (int di = 0; di < 4; ++di)
#pragma unroll
    for (int mi = 0; mi < 2; ++mi)
#pragma unroll
      for (int rr = 0; rr < 4; ++rr) {
        int d = dg * 64 + di * 16 + lg * 4 + rr;
        int ml = mg * 32 + mi * 16 + lq;
        Gj[d * 128 + ml] = f2bf(acc[di][mi][rr]);
      }
}

// ---------------------------------------------------------------------------
// prefix_wfin (unchanged)
// ---------------------------------------------------------------------------
__global__ __launch_bounds__(256) void prefix_wfin(
    u16* __restrict__ G0, u16* __restrict__ G1, float* __restrict__ wfin) {
  __shared__ float Wl[16][132];
  const int b = blockIdx.x, mh = blockIdx.y, ds = blockIdx.z;
  u16* G = mh ? G1 : G0;
  const int tid = threadIdx.x;
  const int mo = tid & 15, dg = tid >> 4;
  const int d = ds * 16 + dg;
  size_t base = (((size_t)b * 16) << 14) + d * 128 + mo * 8;
  float acc[8];
#pragma unroll
  for (int k = 0; k < 8; ++k) acc[k] = ALPHA_INV;
  for (int j = 0; j < 16; ++j) {
    u16* p = G + base + ((size_t)j << 14);
    short8 g = *(short8*)p;
    short8 c;
#pragma unroll
    for (int k = 0; k < 8; ++k) c[k] = (short)f2bf(acc[k]);
    *(short8*)p = c;
#pragma unroll
    for (int k = 0; k < 8; ++k) acc[k] += bf2f((u16)g[k]);
  }
#pragma unroll
  for (int k = 0; k < 8; ++k) Wl[dg][mo * 8 + k] = acc[k];
  __syncthreads();
  const int ml = tid >> 1, dq = tid & 1;
  const int dl0 = dq * 8;
  float* dst = wfin + ((size_t)b * 256 + mh * 128 + ml) * 128 + ds * 16 + dl0;
  float4 v0 = make_float4(Wl[dl0][ml], Wl[dl0 + 1][ml], Wl[dl0 + 2][ml], Wl[dl0 + 3][ml]);
  float4 v1 = make_float4(Wl[dl0 + 4][ml], Wl[dl0 + 5][ml], Wl[dl0 + 6][ml], Wl[dl0 + 7][ml]);
  *(float4*)dst = v0;
  *(float4*)(dst + 4) = v1;
}

// ---------------------------------------------------------------------------
// attn_chunk (R13-proven, 3 barriers, Hi from registers)
// ---------------------------------------------------------------------------
__global__ __launch_bounds__(512) void attn_chunk(
    const u16* __restrict__ H, const u16* __restrict__ ST,
    const u16* __restrict__ C0, const u16* __restrict__ C1,
    float* __restrict__ out) {
  constexpr int M = 256, D = 128, T = 2048;
  __shared__ alignas(16) u16 Hi[128 * 256];
  __shared__ alignas(16) u16 Sl[128 * 128];
  __shared__ alignas(16) u16 Ct[128 * 128];

  const int tid = threadIdx.x;
  const int wid = tid >> 6, lane = tid & 63;
  const int lg = lane >> 4, lq = lane & 15;
  const int b = blockIdx.x, i = blockIdx.y;
  const size_t hrow0 = (size_t)b * T + i * 128;
  const size_t coff = ((size_t)b * 16 + i) * (128 * 128);

  bf16x8 aq[8];
  {
    const u16* qrow = H + (hrow0 + wid * 16 + lq) * M;
#pragma unroll
    for (int ks = 0; ks < 8; ++ks) aq[ks] = *(const bf16x8*)(qrow + ks * 32 + lg * 8);
  }

  short8 ct1r[4];
#pragma unroll
  for (int it = 0; it < 4; ++it) {
    int s = tid + it * 512;
    int d = s >> 4, c8 = s & 15;
    ct1r[it] = *(const short8*)(C1 + coff + d * 128 + c8 * 8);
  }

  {
    int r = wid * 16 + lq;
#pragma unroll
    for (int ks = 0; ks < 8; ++ks)
      *(short8*)((char*)Hi + swz(r * 512 + ks * 64 + lg * 16, r)) =
          __builtin_bit_cast(short8, aq[ks]);
  }
#pragma unroll
  for (int it = 0; it < 4; ++it) {
    int s = tid + it * 512;
    int d = s >> 4, c8 = s & 15;
    *(short8*)((char*)Sl + swz(d * 256 + c8 * 16, d)) =
        *(const short8*)(ST + ((size_t)b * D + d) * T + i * 128 + c8 * 8);
  }
#pragma unroll
  for (int it = 0; it < 4; ++it) {
    int s = tid + it * 512;
    int d = s >> 4, c8 = s & 15;
    *(short8*)((char*)Ct + swz(d * 256 + c8 * 16, d)) = *(const short8*)(C0 + coff + d * 128 + c8 * 8);
  }
  __syncthreads();

  f32x4 accO[8];
#pragma unroll
  for (int df = 0; df < 8; ++df) accO[df] = (f32x4)0.0f;
#pragma unroll
  for (int ks = 0; ks < 4; ++ks)
#pragma unroll
    for (int df = 0; df < 8; ++df) {
      int d = df * 16 + lq;
      bf16x8 bf = *(const bf16x8*)((const char*)Ct + swz(d * 256 + ks * 64 + lg * 16, d));
      accO[df] = mfma(aq[ks], bf, accO[df]);
    }
  f32x4 accP[8];
#pragma unroll
  for (int cf = 0; cf < 8; ++cf) accP[cf] = (f32x4)0.0f;
#pragma unroll
  for (int ks = 0; ks < 8; ++ks)
#pragma unroll
    for (int cf = 0; cf < 8; ++cf) {
      int tt = cf * 16 + lq;
      bf16x8 bf = *(const bf16x8*)((const char*)Hi + swz(tt * 512 + ks * 64 + lg * 16, tt));
      accP[cf] = mfma(aq[ks], bf, accP[cf]);
    }
  __syncthreads();

#pragma unroll
  for (int it = 0; it < 4; ++it) {
    int s = tid + it * 512;
    int d = s >> 4, c8 = s & 15;
    *(short8*)((char*)Ct + swz(d * 256 + c8 * 16, d)) = ct1r[it];
  }
  char* Pw = (char*)Hi + wid * 4096;
#pragma unroll
  for (int cf = 0; cf < 8; ++cf)
#pragma unroll
    for (int rr = 0; rr < 4; ++rr) {
      int ql = lg * 4 + rr;
      int tl = cf * 16 + lq;
      float v = accP[cf][rr];
      if (tl >= wid * 16 + ql) v = 0.0f;
      *(u16*)(Pw + swz(ql * 256 + tl * 2, ql)) = f2bf(v);
    }
  __syncthreads();

#pragma unroll
  for (int ks = 0; ks < 4; ++ks)
#pragma unroll
    for (int df = 0; df < 8; ++df) {
      int d = df * 16 + lq;
      bf16x8 bf = *(const bf16x8*)((const char*)Ct + swz(d * 256 + ks * 64 + lg * 16, d));
      accO[df] = mfma(aq[4 + ks], bf, accO[df]);
    }
#pragma unroll
  for (int ks = 0; ks < 4; ++ks) {
    bf16x8 a = *(const bf16x8*)(Pw + swz(lq * 256 + ks * 64 + lg * 16, lq));
#pragma unroll
    for (int df = 0; df < 8; ++df) {
      int d = df * 16 + lq;
      bf16x8 bf = *(const bf16x8*)((const char*)Sl + swz(d * 256 + ks * 64 + lg * 16, d));
      accO[df] = mfma(a, bf, accO[df]);
    }
  }

#pragma unroll
  for (int rr = 0; rr < 4; ++rr) {
    float ssum = 0.0f;
#pragma unroll
    for (int df = 0; df < 8; ++df) ssum += accO[df][rr];
#pragma unroll
    for (int off = 1; off < 16; off <<= 1) ssum += __shfl_xor(ssum, off);
    float inv = 1.0f / ssum;
    size_t row = hrow0 + wid * 16 + lg * 4 + rr;
#pragma unroll
    for (int df = 0; df < 8; ++df)
      out[row * D + df * 16 + lq] = accO[df][rr] * inv;
  }
}

// ---------------------------------------------------------------------------
extern "C" void kernel_launch(void* const* d_in, const int* in_sizes, int n_in,
                              void* d_out, int out_size, void* d_ws, size_t ws_size,
                              hipStream_t stream) {
  const float* batch = (const float*)d_in[0];
  const float* w0 = (const float*)d_in[1];
  const float* b0 = (const float*)d_in[2];
  const float* w1 = (const float*)d_in[3];
  const float* b1 = (const float*)d_in[4];
  const float* w2 = (const float*)d_in[5];
  const float* b2 = (const float*)d_in[6];
  const float* wo = (const float*)d_in[7];
  const float* bo = (const float*)d_in[8];

  const size_t SZ_S = 16777216;     // 16MB
  const size_t SZ_BUF = 33554432;   // 32MB
  const size_t ST_OFF = 88080384;   // 84MB — ST's own region
  const size_t NEED = ST_OFF + SZ_S;
  if (ws_size < NEED) return;

  char* ws = (char*)d_ws;
  u16* bufA = (u16*)(ws + SZ_S);
  u16* bufB = (u16*)(ws + SZ_S + SZ_BUF);
  u16* Wt0 = (u16*)(ws + SZ_S + 2 * SZ_BUF);
  u16* Wt1 = Wt0 + 2 * 256 * 128;
  u16* Wt2 = Wt1 + 2 * 256 * 256;
  u16* Wt3 = Wt2 + 2 * 256 * 256;
  u16* ST = (u16*)(ws + ST_OFF);
  u16* G0 = (u16*)ws;
  u16* G1 = (u16*)(ws + 2 * SZ_S);
  float* probs = (float*)d_out;
  float* wfin = probs + (size_t)32 * 2048 * 128;

  prep<<<2560, 256, 0, stream>>>(batch, w0, w1, w2, wo, Wt0, Wt1, Wt2, Wt3, ST);

  conv_first<<<512, 512, 0, stream>>>(batch, Wt0, b0, bufA);
  conv_mid<2><<<512, 512, 0, stream>>>(bufA, Wt1, b1, bufB);
  conv_mid<4><<<512, 512, 0, stream>>>(bufB, Wt2, b2, bufA);
  conv_last<<<512, 512, 0, stream>>>(bufA, Wt3, bo, bufB);

  gchunk<<<dim3(32, 2, 16), 512, 0, stream>>>(bufB, ST, G0, G1);
  prefix_wfin<<<dim3(32, 2, 8), 256, 0, stream>>>(G0, G1, wfin);
  attn_chunk<<<dim3(32, 16), 512, 0, stream>>>(bufB, ST, G0, G1, probs);
}

// Round 19
// 172.619 us; speedup vs baseline: 1.0501x; 1.0109x over previous
//
#include <hip/hip_runtime.h>

using u16 = unsigned short;
using u32 = unsigned int;
using short8 = __attribute__((ext_vector_type(8))) short;
using short4v = __attribute__((ext_vector_type(4))) short;
using bf16x8 = __attribute__((ext_vector_type(8))) __bf16;
using f32x4 = __attribute__((ext_vector_type(4))) float;

#define ALPHA_INV (1.0f / (128.0f * 100.0f))

__device__ __forceinline__ u32 swz(u32 off, u32 row) { return off ^ ((row & 7u) << 4); }

__device__ __forceinline__ u16 f2bf(float x) {
  u32 u = __float_as_uint(x);
  u32 r = u + 0x7fffu + ((u >> 16) & 1u);
  return (u16)(r >> 16);
}

__device__ __forceinline__ float bf2f(u16 x) {
  u32 u = ((u32)x) << 16;
  return __uint_as_float(u);
}

__device__ __forceinline__ f32x4 mfma(bf16x8 a, bf16x8 b, f32x4 c) {
  return __builtin_amdgcn_mfma_f32_16x16x32_bf16(a, b, c, 0, 0, 0);
}

// async 16B global->LDS; LDS dest is wave-uniform base + lane*16
__device__ __forceinline__ void gl16(const void* g, void* l) {
  __builtin_amdgcn_global_load_lds(
      (const __attribute__((address_space(1))) unsigned int*)g,
      (__attribute__((address_space(3))) unsigned int*)l, 16, 0, 0);
}

// ---------------------------------------------------------------------------
// prep: weights transpose+bf16+pre-swizzle + batch fp32 -> ST (own region).
// ---------------------------------------------------------------------------
__global__ __launch_bounds__(256) void prep(
    const float* __restrict__ batch,
    const float* __restrict__ w0, const float* __restrict__ w1,
    const float* __restrict__ w2, const float* __restrict__ wo,
    u16* __restrict__ o0, u16* __restrict__ o1,
    u16* __restrict__ o2, u16* __restrict__ o3,
    u16* __restrict__ ST) {
  __shared__ u16 L[64 * 129];
  int blk = blockIdx.x;
  if (blk < 1536) {
    const float* w; u16* o; int cin;
    if (blk < 256)       { w = w0; o = o0; cin = 128; }
    else if (blk < 768)  { w = w1; o = o1; cin = 256; blk -= 256; }
    else if (blk < 1280) { w = w2; o = o2; cin = 256; blk -= 768; }
    else                 { w = wo; o = o3; cin = 256; blk -= 1280; }
    int idx = blk * 256 + threadIdx.x;
    int row = idx >> 8, n = idx & 255;
    int tap = row / cin, c = row - tap * cin;
    int kc = c >> 6, ci = c & 63;
    u32 sb = (u32)(ci * 2) ^ ((u32)(n & 7) << 4);
    o[((size_t)tap * 256 + n) * cin + kc * 64 + (sb >> 1)] = f2bf(w[idx]);
    return;
  }
  blk -= 1536;
  const int tid = threadIdx.x;
  const int t0 = (blk & 31) * 64;
  const int b = blk >> 5;
  const float* src = batch + ((size_t)b * 2048 + t0) * 128;
#pragma unroll
  for (int it = 0; it < 4; ++it) {
    int s = tid + it * 256;
    int t = s >> 4, c8 = s & 15;
    float4 v0 = *(const float4*)(src + t * 128 + c8 * 8);
    float4 v1 = *(const float4*)(src + t * 128 + c8 * 8 + 4);
    u16* p = &L[t * 129 + c8 * 8];
    p[0] = f2bf(v0.x); p[1] = f2bf(v0.y); p[2] = f2bf(v0.z); p[3] = f2bf(v0.w);
    p[4] = f2bf(v1.x); p[5] = f2bf(v1.y); p[6] = f2bf(v1.z); p[7] = f2bf(v1.w);
  }
  __syncthreads();
  u16* dst = ST + (size_t)b * 128 * 2048 + t0;
#pragma unroll
  for (int it = 0; it < 4; ++it) {
    int s = tid + it * 256;
    int oct = s & 7, d = s >> 3;
    short8 v;
#pragma unroll
    for (int j = 0; j < 8; ++j) v[j] = (short)L[(oct * 8 + j) * 129 + d];
    *(short8*)(dst + (size_t)d * 2048 + oct * 8) = v;
  }
}

// ---------------------------------------------------------------------------
// conv_first, 2-PHASE 3-buffer: B prefetched 2 tiles ahead (gl16); A (fp32
// reg path + convert) written 1 tile ahead. Rotation-safe as in conv_mid.
// ---------------------------------------------------------------------------
__global__ __launch_bounds__(512) void conv_first(
    const float* __restrict__ in, const u16* __restrict__ wt,
    const float* __restrict__ bias, u16* __restrict__ out) {
  constexpr int CIN = 128, BN = 256;
  __shared__ alignas(16) u16 Al[3][128 * 64];
  __shared__ alignas(16) u16 Bl[3][256 * 64];

  const int tid = threadIdx.x;
  const int wid = tid >> 6, lane = tid & 63;
  const int wr = wid >> 2, wc = wid & 3;
  const int lg = lane >> 4, lq = lane & 15;
  const int row0 = blockIdx.x * 128;
  const int tloc0 = row0 & 2047;

  f32x4 acc[4][4];
#pragma unroll
  for (int i = 0; i < 4; ++i)
#pragma unroll
    for (int j = 0; j < 4; ++j) acc[i][j] = (f32x4)0.0f;

// tile T: tap = T>>1, kc = T&1, shift = 1-tap
#define WRITE_A(BUF, T)                                                                  \
  {                                                                                      \
    const int tap_ = (T) >> 1, kc_ = (T) & 1, shift_ = 1 - tap_;                         \
    _Pragma("unroll") for (int it = 0; it < 2; ++it) {                                   \
      int gi = tid + it * 512;                                                           \
      int r = gi >> 3, cg = gi & 7;                                                      \
      short8 v = (short8)0;                                                              \
      if (!(tloc0 == 0 && r < shift_)) {                                                 \
        const float* src = in + (size_t)(row0 + r - shift_) * CIN + kc_ * 64 + cg * 8;   \
        float4 a = *(const float4*)src;                                                  \
        float4 b2 = *(const float4*)(src + 4);                                           \
        v[0] = (short)f2bf(a.x);  v[1] = (short)f2bf(a.y);                               \
        v[2] = (short)f2bf(a.z);  v[3] = (short)f2bf(a.w);                               \
        v[4] = (short)f2bf(b2.x); v[5] = (short)f2bf(b2.y);                              \
        v[6] = (short)f2bf(b2.z); v[7] = (short)f2bf(b2.w);                              \
      }                                                                                  \
      *(short8*)((char*)Al[BUF] + swz(r * 128 + cg * 16, (u32)(r - shift_ + 8))) = v;    \
    }                                                                                    \
  }

#define STAGE_B1(BUF, T)                                                                 \
  {                                                                                      \
    const int tap_ = (T) >> 1, kc_ = (T) & 1;                                            \
    const u16* wtb = wt + (size_t)(tap_ * 256) * CIN + kc_ * 64;                         \
    _Pragma("unroll") for (int p = 0; p < 4; ++p) {                                      \
      int gi = tid + p * 512;                                                            \
      gl16(wtb + (size_t)(gi >> 3) * CIN + (gi & 7) * 8,                                 \
           (char*)Bl[BUF] + p * 8192 + wid * 1024);                                      \
    }                                                                                    \
  }

  STAGE_B1(0, 0);
  STAGE_B1(1, 1);
  WRITE_A(0, 0);  // implicit reg-dep wait drains B(0),B(1) too (older in FIFO)
  asm volatile("s_waitcnt vmcnt(0) lgkmcnt(0)" ::: "memory");
  __builtin_amdgcn_s_barrier();

#pragma unroll
  for (int t = 0; t < 4; ++t) {
    const int buf = t % 3;
    const int shift = 1 - (t >> 1);
#pragma unroll
    for (int ks = 0; ks < 2; ++ks) {
      bf16x8 af[4], bfr[4];
#pragma unroll
      for (int mi = 0; mi < 4; ++mi) {
        int r = wr * 64 + mi * 16 + lq;
        af[mi] = *(const bf16x8*)((const char*)Al[buf] +
                                  swz(r * 128 + ks * 64 + lg * 16, (u32)(r - shift + 8)));
      }
#pragma unroll
      for (int ni = 0; ni < 4; ++ni) {
        int n = wc * 64 + ni * 16 + lq;
        bfr[ni] = *(const bf16x8*)((const char*)Bl[buf] + swz(n * 128 + ks * 64 + lg * 16, n));
      }
#pragma unroll
      for (int mi = 0; mi < 4; ++mi)
#pragma unroll
        for (int ni = 0; ni < 4; ++ni)
          acc[mi][ni] = mfma(af[mi], bfr[ni], acc[mi][ni]);
    }
    if (t < 3) {
      WRITE_A((t + 1) % 3, t + 1);        // A reg-loads drain older vmem
      if (t < 2) {
        STAGE_B1((t + 2) % 3, t + 2);     // only B(t+2) outstanding now
        asm volatile("s_waitcnt vmcnt(4) lgkmcnt(0)" ::: "memory");
      } else {
        asm volatile("s_waitcnt vmcnt(0) lgkmcnt(0)" ::: "memory");
      }
      __builtin_amdgcn_s_barrier();
    }
  }
#undef WRITE_A
#undef STAGE_B1

  float bcol[4];
#pragma unroll
  for (int ni = 0; ni < 4; ++ni) bcol[ni] = bias[wc * 64 + ni * 16 + lq];
#pragma unroll
  for (int mi = 0; mi < 4; ++mi)
#pragma unroll
    for (int ni = 0; ni < 4; ++ni)
#pragma unroll
      for (int rr = 0; rr < 4; ++rr) {
        float v = fmaxf(acc[mi][ni][rr] + bcol[ni], 0.0f);
        int row = row0 + wr * 64 + mi * 16 + lg * 4 + rr;
        int col = wc * 64 + ni * 16 + lq;
        int ci = col & 63;
        u32 sb = (u32)(ci * 2) ^ ((u32)(row & 7) << 4);
        out[(size_t)row * BN + wc * 64 + (sb >> 1)] = f2bf(v);
      }
}

// ---------------------------------------------------------------------------
// conv_mid<DIL>, 2-PHASE with 3-BUFFER rotation (R18-proven).
// ---------------------------------------------------------------------------
template <int DIL>
__global__ __launch_bounds__(512) void conv_mid(
    const u16* __restrict__ in, const u16* __restrict__ wt,
    const float* __restrict__ bias, u16* __restrict__ out) {
  constexpr int CIN = 256, BN = 256;
  __shared__ alignas(16) u16 Al[3][136 * 64];
  __shared__ alignas(16) u16 Bl[3][256 * 64];

  const int tid = threadIdx.x;
  const int wid = tid >> 6, lane = tid & 63;
  const int wr = wid >> 2, wc = wid & 3;
  const int lg = lane >> 4, lq = lane & 15;
  const int row0 = blockIdx.x * 128;
  const int tloc0 = row0 & 2047;

  f32x4 acc[4][4];
#pragma unroll
  for (int i = 0; i < 4; ++i)
#pragma unroll
    for (int j = 0; j < 4; ++j) acc[i][j] = (f32x4)0.0f;

#define STAGE_MID(BUF, KC, TAP)                                                          \
  {                                                                                      \
    _Pragma("unroll") for (int p = 0; p < 2; ++p) {                                      \
      int gi = tid + p * 512;                                                            \
      gl16(in + (size_t)(row0 - DIL + (gi >> 3)) * CIN + (KC)*64 + (gi & 7) * 8,         \
           (char*)Al[BUF] + p * 8192 + wid * 1024);                                      \
    }                                                                                    \
    if (wid == 0)                                                                        \
      gl16(in + (size_t)(row0 - DIL + 128 + (lane >> 3)) * CIN + (KC)*64 + (lane & 7) * 8,\
           (char*)Al[BUF] + 16384);                                                      \
    const u16* wtb = wt + (size_t)(TAP)*256 * CIN + (KC)*64;                             \
    _Pragma("unroll") for (int p = 0; p < 4; ++p) {                                      \
      int gi = tid + p * 512;                                                            \
      gl16(wtb + (size_t)(gi >> 3) * CIN + (gi & 7) * 8,                                 \
           (char*)Bl[BUF] + p * 8192 + wid * 1024);                                      \
    }                                                                                    \
  }

  STAGE_MID(0, 0, 0);          // tile 0 = (kc0, tap0)
  STAGE_MID(1, 0, 1);          // tile 1 = (kc0, tap1)
  if (wid == 0)
    asm volatile("s_waitcnt vmcnt(7)" ::: "memory");   // tile 0 landed
  else
    asm volatile("s_waitcnt vmcnt(6)" ::: "memory");
  __builtin_amdgcn_s_barrier();

#pragma unroll
  for (int it8 = 0; it8 < 8; ++it8) {
    const int buf = it8 % 3;
    const int tap = it8 & 1;
    if (tap == 0 && tloc0 == 0) {  // zero garbage rows < DIL (block-uniform)
      if (tid < DIL * 8) *(short8*)((char*)Al[buf] + tid * 16) = (short8)0;
      asm volatile("s_waitcnt lgkmcnt(0)" ::: "memory");
      __builtin_amdgcn_s_barrier();
    }
#pragma unroll
    for (int ks = 0; ks < 2; ++ks) {
      bf16x8 af[4], bfr[4];
#pragma unroll
      for (int mi = 0; mi < 4; ++mi) {
        int r = wr * 64 + mi * 16 + lq;
        if (tap == 0)
          af[mi] = *(const bf16x8*)((const char*)Al[buf] +
                                    swz(r * 128 + ks * 64 + lg * 16, (u32)(r - DIL + 8)));
        else
          af[mi] = *(const bf16x8*)((const char*)Al[buf] +
                                    swz((r + DIL) * 128 + ks * 64 + lg * 16, (u32)(r + 8)));
      }
#pragma unroll
      for (int ni = 0; ni < 4; ++ni) {
        int n = wc * 64 + ni * 16 + lq;
        bfr[ni] = *(const bf16x8*)((const char*)Bl[buf] + swz(n * 128 + ks * 64 + lg * 16, n));
      }
#pragma unroll
      for (int mi = 0; mi < 4; ++mi)
#pragma unroll
        for (int ni = 0; ni < 4; ++ni)
          acc[mi][ni] = mfma(af[mi], bfr[ni], acc[mi][ni]);
    }
    if (it8 < 6) {
      STAGE_MID((it8 + 2) % 3, (it8 + 2) >> 1, (it8 + 2) & 1);
    }
    if (it8 < 7) {
      if (it8 < 6) {
        if (wid == 0)
          asm volatile("s_waitcnt vmcnt(7)" ::: "memory");  // tile it8+1 landed
        else
          asm volatile("s_waitcnt vmcnt(6)" ::: "memory");
      } else {
        asm volatile("s_waitcnt vmcnt(0)" ::: "memory");    // last tile landed
      }
      __builtin_amdgcn_s_barrier();
    }
  }
#undef STAGE_MID

  float bcol[4];
#pragma unroll
  for (int ni = 0; ni < 4; ++ni) bcol[ni] = bias[wc * 64 + ni * 16 + lq];
#pragma unroll
  for (int mi = 0; mi < 4; ++mi)
#pragma unroll
    for (int ni = 0; ni < 4; ++ni)
#pragma unroll
      for (int rr = 0; rr < 4; ++rr) {
        float v = fmaxf(acc[mi][ni][rr] + bcol[ni], 0.0f);
        int row = row0 + wr * 64 + mi * 16 + lg * 4 + rr;
        int col = wc * 64 + ni * 16 + lq;
        int ci = col & 63;
        u32 sb = (u32)(ci * 2) ^ ((u32)(row & 7) << 4);
        out[(size_t)row * BN + wc * 64 + (sb >> 1)] = f2bf(v);
      }
}

// ---------------------------------------------------------------------------
// conv_last, 2-PHASE with 3-buffer rotation. Fused softmax epilogue.
// ---------------------------------------------------------------------------
__global__ __launch_bounds__(512) void conv_last(
    const u16* __restrict__ in, const u16* __restrict__ wt,
    const float* __restrict__ bias, u16* __restrict__ out) {
  constexpr int CIN = 256, BN = 256;
  __shared__ alignas(16) u16 Al[3][128 * 64];
  __shared__ alignas(16) u16 Bl[3][256 * 64];
  __shared__ float redA[4][128];
  __shared__ float redB[4][128];

  const int tid = threadIdx.x;
  const int wid = tid >> 6, lane = tid & 63;
  const int wr = wid >> 2, wc = wid & 3;
  const int lg = lane >> 4, lq = lane & 15;
  const int row0 = blockIdx.x * 128;

  f32x4 acc[4][4];
#pragma unroll
  for (int i = 0; i < 4; ++i)
#pragma unroll
    for (int j = 0; j < 4; ++j) acc[i][j] = (f32x4)0.0f;

#define STAGE_LAST(BUF, KC)                                                              \
  {                                                                                      \
    _Pragma("unroll") for (int p = 0; p < 2; ++p) {                                      \
      int gi = tid + p * 512;                                                            \
      gl16(in + (size_t)(row0 + (gi >> 3)) * CIN + (KC)*64 + (gi & 7) * 8,               \
           (char*)Al[BUF] + p * 8192 + wid * 1024);                                      \
    }                                                                                    \
    const u16* wtb = wt + (KC)*64;                                                       \
    _Pragma("unroll") for (int p = 0; p < 4; ++p) {                                      \
      int gi = tid + p * 512;                                                            \
      gl16(wtb + (size_t)(gi >> 3) * CIN + (gi & 7) * 8,                                 \
           (char*)Bl[BUF] + p * 8192 + wid * 1024);                                      \
    }                                                                                    \
  }

  STAGE_LAST(0, 0);
  STAGE_LAST(1, 1);
  asm volatile("s_waitcnt vmcnt(6)" ::: "memory");  // tile 0 landed
  __builtin_amdgcn_s_barrier();

#pragma unroll
  for (int it4 = 0; it4 < 4; ++it4) {
    const int buf = it4 % 3;
#pragma unroll
    for (int ks = 0; ks < 2; ++ks) {
      bf16x8 af[4], bfr[4];
#pragma unroll
      for (int mi = 0; mi < 4; ++mi) {
        int r = wr * 64 + mi * 16 + lq;
        af[mi] = *(const bf16x8*)((const char*)Al[buf] +
                                  swz(r * 128 + ks * 64 + lg * 16, (u32)(r + 8)));
      }
#pragma unroll
      for (int ni = 0; ni < 4; ++ni) {
        int n = wc * 64 + ni * 16 + lq;
        bfr[ni] = *(const bf16x8*)((const char*)Bl[buf] + swz(n * 128 + ks * 64 + lg * 16, n));
      }
#pragma unroll
      for (int mi = 0; mi < 4; ++mi)
#pragma unroll
        for (int ni = 0; ni < 4; ++ni)
          acc[mi][ni] = mfma(af[mi], bfr[ni], acc[mi][ni]);
    }
    if (it4 < 2) {
      STAGE_LAST((it4 + 2) % 3, it4 + 2);
    }
    if (it4 < 3) {
      if (it4 < 2)
        asm volatile("s_waitcnt vmcnt(6)" ::: "memory");
      else
        asm volatile("s_waitcnt vmcnt(0)" ::: "memory");
      __builtin_amdgcn_s_barrier();
    }
  }
#undef STAGE_LAST
  __syncthreads();

  float bcol[4];
#pragma unroll
  for (int ni = 0; ni < 4; ++ni) bcol[ni] = bias[wc * 64 + ni * 16 + lq];
#pragma unroll
  for (int mi = 0; mi < 4; ++mi)
#pragma unroll
    for (int ni = 0; ni < 4; ++ni)
#pragma unroll
      for (int rr = 0; rr < 4; ++rr) acc[mi][ni][rr] += bcol[ni];

  float tmx[4][4];
#pragma unroll
  for (int mi = 0; mi < 4; ++mi)
#pragma unroll
    for (int rr = 0; rr < 4; ++rr) {
      float v = fmaxf(fmaxf(acc[mi][0][rr], acc[mi][1][rr]),
                      fmaxf(acc[mi][2][rr], acc[mi][3][rr]));
#pragma unroll
      for (int off = 1; off < 16; off <<= 1) v = fmaxf(v, __shfl_xor(v, off));
      if (lq == 0) redA[wc][wr * 64 + mi * 16 + lg * 4 + rr] = v;
    }
  __syncthreads();
#pragma unroll
  for (int mi = 0; mi < 4; ++mi)
#pragma unroll
    for (int rr = 0; rr < 4; ++rr) {
      int rb = wr * 64 + mi * 16 + lg * 4 + rr;
      tmx[mi][rr] = fmaxf(fmaxf(redA[0][rb], redA[1][rb]),
                          fmaxf(redA[2][rb], redA[3][rb]));
    }
#pragma unroll
  for (int mi = 0; mi < 4; ++mi)
#pragma unroll
    for (int rr = 0; rr < 4; ++rr) {
      float s = 0.0f;
#pragma unroll
      for (int ni = 0; ni < 4; ++ni) {
        float p = __expf(acc[mi][ni][rr] - tmx[mi][rr]);
        acc[mi][ni][rr] = p;
        s += p;
      }
#pragma unroll
      for (int off = 1; off < 16; off <<= 1) s += __shfl_xor(s, off);
      if (lq == 0) redB[wc][wr * 64 + mi * 16 + lg * 4 + rr] = s;
    }
  __syncthreads();
#pragma unroll
  for (int mi = 0; mi < 4; ++mi)
#pragma unroll
    for (int rr = 0; rr < 4; ++rr) {
      int rb = wr * 64 + mi * 16 + lg * 4 + rr;
      float inv = 1.0f / (redB[0][rb] + redB[1][rb] + redB[2][rb] + redB[3][rb]);
      int row = row0 + rb;
#pragma unroll
      for (int ni = 0; ni < 4; ++ni) {
        int col = wc * 64 + ni * 16 + lq;
        out[(size_t)row * BN + col] = f2bf(acc[mi][ni][rr] * inv);
      }
    }
}

// ---------------------------------------------------------------------------
// gchunk (unchanged)
// ---------------------------------------------------------------------------
__global__ __launch_bounds__(512) void gchunk(
    const u16* __restrict__ H, const u16* __restrict__ ST,
    u16* __restrict__ G0, u16* __restrict__ G1) {
  constexpr int M = 256, T = 2048;
  __shared__ alignas(16) u16 Hl[128 * 128];
  __shared__ alignas(16) u16 Sl[128 * 128];
  const int tid = threadIdx.x;
  const int wid = tid >> 6, lane = tid & 63;
  const int dg = wid >> 2, mg = wid & 3;
  const int lg = lane >> 4, lq = lane & 15;
  const int b = blockIdx.x, mh = blockIdx.y, j = blockIdx.z;
  u16* G = (mh == 0 ? G0 : G1);

#pragma unroll
  for (int it = 0; it < 4; ++it) {
    int s = tid + it * 512;
    int t = s >> 4, c8 = s & 15;
    short8 v = *(const short8*)(H + ((size_t)b * T + j * 128 + t) * M + mh * 128 + c8 * 8);
#pragma unroll
    for (int jj = 0; jj < 8; ++jj) {
      int ml = c8 * 8 + jj;
      *(u16*)((char*)Hl + swz(ml * 256 + t * 2, ml)) = (u16)v[jj];
    }
  }
#pragma unroll
  for (int it = 0; it < 4; ++it) {
    int s = tid + it * 512;
    int d = s >> 4, c8 = s & 15;
    *(short8*)((char*)Sl + swz(d * 256 + c8 * 16, d)) =
        *(const short8*)(ST + ((size_t)b * 128 + d) * T + j * 128 + c8 * 8);
  }
  __syncthreads();

  f32x4 acc[4][2];
#pragma unroll
  for (int di = 0; di < 4; ++di)
#pragma unroll
    for (int mi = 0; mi < 2; ++mi) acc[di][mi] = (f32x4)0.0f;

#pragma unroll
  for (int ks = 0; ks < 4; ++ks) {
    bf16x8 sfrag[4];
#pragma unroll
    for (int di = 0; di < 4; ++di) {
      int d = dg * 64 + di * 16 + lq;
      sfrag[di] = *(const bf16x8*)((const char*)Sl + swz(d * 256 + ks * 64 + lg * 16, d));
    }
#pragma unroll
    for (int mi = 0; mi < 2; ++mi) {
      int ml = mg * 32 + mi * 16 + lq;
      bf16x8 hfrag =
          *(const bf16x8*)((const char*)Hl + swz(ml * 256 + ks * 64 + lg * 16, ml));
#pragma unroll
      for (int di = 0; di < 4; ++di) acc[di][mi] = mfma(sfrag[di], hfrag, acc[di][mi]);
    }
  }

  u16* Gj = G + (((size_t)b * 16 + j) << 14);
#pragma unroll
  for (int di = 0; di < 4; ++di)
#pragma unroll
    for (int mi = 0; mi < 2; ++mi)
#pragma unroll
      for (int rr = 0; rr < 4; ++rr) {
        int d = dg * 64 + di * 16 + lg * 4 + rr;
        int ml = mg * 32 + mi * 16 + lq;
        Gj[d * 128 + ml] = f2bf(acc[di][mi][rr]);
      }
}

// ---------------------------------------------------------------------------
// prefix_wfin (unchanged)
// ---------------------------------------------------------------------------
__global__ __launch_bounds__(256) void prefix_wfin(
    u16* __restrict__ G0, u16* __restrict__ G1, float* __restrict__ wfin) {
  __shared__ float Wl[16][132];
  const int b = blockIdx.x, mh = blockIdx.y, ds = blockIdx.z;
  u16* G = mh ? G1 : G0;
  const int tid = threadIdx.x;
  const int mo = tid & 15, dg = tid >> 4;
  const int d = ds * 16 + dg;
  size_t base = (((size_t)b * 16) << 14) + d * 128 + mo * 8;
  float acc[8];
#pragma unroll
  for (int k = 0; k < 8; ++k) acc[k] = ALPHA_INV;
  for (int j = 0; j < 16; ++j) {
    u16* p = G + base + ((size_t)j << 14);
    short8 g = *(short8*)p;
    short8 c;
#pragma unroll
    for (int k = 0; k < 8; ++k) c[k] = (short)f2bf(acc[k]);
    *(short8*)p = c;
#pragma unroll
    for (int k = 0; k < 8; ++k) acc[k] += bf2f((u16)g[k]);
  }
#pragma unroll
  for (int k = 0; k < 8; ++k) Wl[dg][mo * 8 + k] = acc[k];
  __syncthreads();
  const int ml = tid >> 1, dq = tid & 1;
  const int dl0 = dq * 8;
  float* dst = wfin + ((size_t)b * 256 + mh * 128 + ml) * 128 + ds * 16 + dl0;
  float4 v0 = make_float4(Wl[dl0][ml], Wl[dl0 + 1][ml], Wl[dl0 + 2][ml], Wl[dl0 + 3][ml]);
  float4 v1 = make_float4(Wl[dl0 + 4][ml], Wl[dl0 + 5][ml], Wl[dl0 + 6][ml], Wl[dl0 + 7][ml]);
  *(float4*)dst = v0;
  *(float4*)(dst + 4) = v1;
}

// ---------------------------------------------------------------------------
// attn_chunk (R13-proven, 3 barriers, Hi from registers)
// ---------------------------------------------------------------------------
__global__ __launch_bounds__(512) void attn_chunk(
    const u16* __restrict__ H, const u16* __restrict__ ST,
    const u16* __restrict__ C0, const u16* __restrict__ C1,
    float* __restrict__ out) {
  constexpr int M = 256, D = 128, T = 2048;
  __shared__ alignas(16) u16 Hi[128 * 256];
  __shared__ alignas(16) u16 Sl[128 * 128];
  __shared__ alignas(16) u16 Ct[128 * 128];

  const int tid = threadIdx.x;
  const int wid = tid >> 6, lane = tid & 63;
  const int lg = lane >> 4, lq = lane & 15;
  const int b = blockIdx.x, i = blockIdx.y;
  const size_t hrow0 = (size_t)b * T + i * 128;
  const size_t coff = ((size_t)b * 16 + i) * (128 * 128);

  bf16x8 aq[8];
  {
    const u16* qrow = H + (hrow0 + wid * 16 + lq) * M;
#pragma unroll
    for (int ks = 0; ks < 8; ++ks) aq[ks] = *(const bf16x8*)(qrow + ks * 32 + lg * 8);
  }

  short8 ct1r[4];
#pragma unroll
  for (int it = 0; it < 4; ++it) {
    int s = tid + it * 512;
    int d = s >> 4, c8 = s & 15;
    ct1r[it] = *(const short8*)(C1 + coff + d * 128 + c8 * 8);
  }

  {
    int r = wid * 16 + lq;
#pragma unroll
    for (int ks = 0; ks < 8; ++ks)
      *(short8*)((char*)Hi + swz(r * 512 + ks * 64 + lg * 16, r)) =
          __builtin_bit_cast(short8, aq[ks]);
  }
#pragma unroll
  for (int it = 0; it < 4; ++it) {
    int s = tid + it * 512;
    int d = s >> 4, c8 = s & 15;
    *(short8*)((char*)Sl + swz(d * 256 + c8 * 16, d)) =
        *(const short8*)(ST + ((size_t)b * D + d) * T + i * 128 + c8 * 8);
  }
#pragma unroll
  for (int it = 0; it < 4; ++it) {
    int s = tid + it * 512;
    int d = s >> 4, c8 = s & 15;
    *(short8*)((char*)Ct + swz(d * 256 + c8 * 16, d)) = *(const short8*)(C0 + coff + d * 128 + c8 * 8);
  }
  __syncthreads();

  f32x4 accO[8];
#pragma unroll
  for (int df = 0; df < 8; ++df) accO[df] = (f32x4)0.0f;
#pragma unroll
  for (int ks = 0; ks < 4; ++ks)
#pragma unroll
    for (int df = 0; df < 8; ++df) {
      int d = df * 16 + lq;
      bf16x8 bf = *(const bf16x8*)((const char*)Ct + swz(d * 256 + ks * 64 + lg * 16, d));
      accO[df] = mfma(aq[ks], bf, accO[df]);
    }
  f32x4 accP[8];
#pragma unroll
  for (int cf = 0; cf < 8; ++cf) accP[cf] = (f32x4)0.0f;
#pragma unroll
  for (int ks = 0; ks < 8; ++ks)
#pragma unroll
    for (int cf = 0; cf < 8; ++cf) {
      int tt = cf * 16 + lq;
      bf16x8 bf = *(const bf16x8*)((const char*)Hi + swz(tt * 512 + ks * 64 + lg * 16, tt));
      accP[cf] = mfma(aq[ks], bf, accP[cf]);
    }
  __syncthreads();

#pragma unroll
  for (int it = 0; it < 4; ++it) {
    int s = tid + it * 512;
    int d = s >> 4, c8 = s & 15;
    *(short8*)((char*)Ct + swz(d * 256 + c8 * 16, d)) = ct1r[it];
  }
  char* Pw = (char*)Hi + wid * 4096;
#pragma unroll
  for (int cf = 0; cf < 8; ++cf)
#pragma unroll
    for (int rr = 0; rr < 4; ++rr) {
      int ql = lg * 4 + rr;
      int tl = cf * 16 + lq;
      float v = accP[cf][rr];
      if (tl >= wid * 16 + ql) v = 0.0f;
      *(u16*)(Pw + swz(ql * 256 + tl * 2, ql)) = f2bf(v);
    }
  __syncthreads();

#pragma unroll
  for (int ks = 0; ks < 4; ++ks)
#pragma unroll
    for (int df = 0; df < 8; ++df) {
      int d = df * 16 + lq;
      bf16x8 bf = *(const bf16x8*)((const char*)Ct + swz(d * 256 + ks * 64 + lg * 16, d));
      accO[df] = mfma(aq[4 + ks], bf, accO[df]);
    }
#pragma unroll
  for (int ks = 0; ks < 4; ++ks) {
    bf16x8 a = *(const bf16x8*)(Pw + swz(lq * 256 + ks * 64 + lg * 16, lq));
#pragma unroll
    for (int df = 0; df < 8; ++df) {
      int d = df * 16 + lq;
      bf16x8 bf = *(const bf16x8*)((const char*)Sl + swz(d * 256 + ks * 64 + lg * 16, d));
      accO[df] = mfma(a, bf, accO[df]);
    }
  }

#pragma unroll
  for (int rr = 0; rr < 4; ++rr) {
    float ssum = 0.0f;
#pragma unroll
    for (int df = 0; df < 8; ++df) ssum += accO[df][rr];
#pragma unroll
    for (int off = 1; off < 16; off <<= 1) ssum += __shfl_xor(ssum, off);
    float inv = 1.0f / ssum;
    size_t row = hrow0 + wid * 16 + lg * 4 + rr;
#pragma unroll
    for (int df = 0; df < 8; ++df)
      out[row * D + df * 16 + lq] = accO[df][rr] * inv;
  }
}

// ---------------------------------------------------------------------------
extern "C" void kernel_launch(void* const* d_in, const int* in_sizes, int n_in,
                              void* d_out, int out_size, void* d_ws, size_t ws_size,
                              hipStream_t stream) {
  const float* batch = (const float*)d_in[0];
  const float* w0 = (const float*)d_in[1];
  const float* b0 = (const float*)d_in[2];
  const float* w1 = (const float*)d_in[3];
  const float* b1 = (const float*)d_in[4];
  const float* w2 = (const float*)d_in[5];
  const float* b2 = (const float*)d_in[6];
  const float* wo = (const float*)d_in[7];
  const float* bo = (const float*)d_in[8];

  const size_t SZ_S = 16777216;     // 16MB
  const size_t SZ_BUF = 33554432;   // 32MB
  const size_t ST_OFF = 88080384;   // 84MB — ST's own region
  const size_t NEED = ST_OFF + SZ_S;
  if (ws_size < NEED) return;

  char* ws = (char*)d_ws;
  u16* bufA = (u16*)(ws + SZ_S);
  u16* bufB = (u16*)(ws + SZ_S + SZ_BUF);
  u16* Wt0 = (u16*)(ws + SZ_S + 2 * SZ_BUF);
  u16* Wt1 = Wt0 + 2 * 256 * 128;
  u16* Wt2 = Wt1 + 2 * 256 * 256;
  u16* Wt3 = Wt2 + 2 * 256 * 256;
  u16* ST = (u16*)(ws + ST_OFF);
  u16* G0 = (u16*)ws;
  u16* G1 = (u16*)(ws + 2 * SZ_S);
  float* probs = (float*)d_out;
  float* wfin = probs + (size_t)32 * 2048 * 128;

  prep<<<2560, 256, 0, stream>>>(batch, w0, w1, w2, wo, Wt0, Wt1, Wt2, Wt3, ST);

  conv_first<<<512, 512, 0, stream>>>(batch, Wt0, b0, bufA);
  conv_mid<2><<<512, 512, 0, stream>>>(bufA, Wt1, b1, bufB);
  conv_mid<4><<<512, 512, 0, stream>>>(bufB, Wt2, b2, bufA);
  conv_last<<<512, 512, 0, stream>>>(bufA, Wt3, bo, bufB);

  gchunk<<<dim3(32, 2, 16), 512, 0, stream>>>(bufB, ST, G0, G1);
  prefix_wfin<<<dim3(32, 2, 8), 256, 0, stream>>>(G0, G1, wfin);
  attn_chunk<<<dim3(32, 16), 512, 0, stream>>>(bufB, ST, G0, G1, probs);
}